// Round 6
// baseline (207.983 us; speedup 1.0000x reference)
//
#include <hip/hip_runtime.h>
#include <math.h>

#define K_CODES 1024
#define D_DIM   64
#define N_PTS   65536
#define HW      4096
#define BSTRIDE 262144   // 64*4096 elements per batch image
#define CHUNK   128

// output offsets (floats)
#define OFF_EQ    0
#define OFF_IDX   4194304
#define OFF_LOSS  4259840
#define OFF_STATS 4259841
#define OFF_EMB   4259843
#define OFF_CSB   4325379
#define OFF_EAB   4326403

// workspace layout (float slots)
#define WS_LOSS 0
#define WS_NVAL 1
#define WS_SCS  2
#define WS_CNT  4
#define WS_ESQ  1028
#define WS_RAND 2052
#define WS_EHI  3076                   // 65536 ushort, swizzled bf16-hi codebook (dead after assign)
#define WS_ELO  35844                  // 65536 ushort, swizzled bf16-lo
#define WS_BASE WS_EHI                 // int[1032], overlays EHI after assign
#define WS_CURS (WS_EHI + 1040)        // int[1024]
#define WS_PART 68612                  // 5 arrays of N: s1,i1,s2,i2,s3
#define WS_SORT WS_PART                // int[N], overlays part after combine
#define WS_ZT   (WS_PART + 5 * N_PTS)  // transposed z: [N][64]

// fp32-exact fallback thresholds
#define M_RESCORE 0.01f
#define M_FULL    5e-4f
// MFMA-approx thresholds (dist error bound ~3e-3)
#define MX_RESCORE 0.05f
#define MX_FULL    8e-3f

typedef __attribute__((ext_vector_type(8))) __bf16 bf16x8;
typedef __attribute__((ext_vector_type(4))) float  f32x4;

// ---------------- bf16 split helpers ----------------
__device__ __forceinline__ unsigned short f2bf_rne(float x) {
  unsigned u = __float_as_uint(x);
  unsigned r = u + 0x7FFFu + ((u >> 16) & 1u);
  return (unsigned short)(r >> 16);
}
__device__ __forceinline__ float bf2f(unsigned short h) {
  return __uint_as_float(((unsigned)h) << 16);
}

// ---------------- threefry2x32 (JAX-compatible) ----------------
__device__ __forceinline__ void tf_block(unsigned k0, unsigned k1,
                                         unsigned& x0, unsigned& x1) {
  unsigned ks2 = k0 ^ k1 ^ 0x1BD11BDAu;
  x0 += k0; x1 += k1;
#define RR(r) { x0 += x1; x1 = (x1 << r) | (x1 >> (32 - r)); x1 ^= x0; }
  RR(13) RR(15) RR(26) RR(6)
  x0 += k1; x1 += ks2 + 1u;
  RR(17) RR(29) RR(16) RR(24)
  x0 += ks2; x1 += k0 + 2u;
  RR(13) RR(15) RR(26) RR(6)
  x0 += k0; x1 += k1 + 3u;
  RR(17) RR(29) RR(16) RR(24)
  x0 += k1; x1 += ks2 + 4u;
  RR(13) RR(15) RR(26) RR(6)
  x0 += ks2; x1 += k0 + 5u;
#undef RR
}

__device__ __forceinline__ unsigned tf_rand_bits(int c) {
  unsigned a0 = 0u, a1 = 2u; tf_block(0u, 1u, a0, a1);
  unsigned b0 = 1u, b1 = 3u; tf_block(0u, 1u, b0, b1);
  unsigned K0 = a1, K1 = b1;
  unsigned x0, x1;
  if (c < 512) { x0 = (unsigned)c; x1 = (unsigned)(512 + c); tf_block(K0, K1, x0, x1); return x0; }
  else         { x0 = (unsigned)(c - 512); x1 = (unsigned)c; tf_block(K0, K1, x0, x1); return x1; }
}

// ---------------- K0: codebook squared norms ----------------
__global__ void k_esq(const float* __restrict__ E, float* __restrict__ esq) {
  int c = blockIdx.x * blockDim.x + threadIdx.x;
  if (c >= K_CODES) return;
  const float4* e4 = reinterpret_cast<const float4*>(E + c * D_DIM);
  float s = 0.f;
#pragma unroll
  for (int j = 0; j < 16; ++j) {
    float4 v = e4[j];
    s += v.x * v.x + v.y * v.y + v.z * v.z + v.w * v.w;
  }
  esq[c] = s;
}

// ---------------- K0b: split codebook into swizzled bf16 hi/lo ----------------
__global__ __launch_bounds__(256) void k_cvt(const float* __restrict__ E,
                                             unsigned short* __restrict__ ehi,
                                             unsigned short* __restrict__ elo) {
  int idx = blockIdx.x * 256 + threadIdx.x;  // 0..65535
  int c = idx >> 6, k = idx & 63;
  float v = E[idx];
  unsigned short h = f2bf_rne(v);
  unsigned short l = f2bf_rne(v - bf2f(h));
  int pos = (c << 6) | (k ^ ((c & 7) << 3));  // XOR-swizzle (16B granules)
  ehi[pos] = h;
  elo[pos] = l;
}

// ---------------- top-3 insert: min + 2x med3 + 2 cmp + 3 cndmask ----------------
__device__ __forceinline__ void ins3(float x, float ix, float& s1, float& s2,
                                     float& s3, float& i1, float& i2) {
  bool c1 = x < s1;
  bool c2 = x < s2;
  float n2 = __builtin_amdgcn_fmed3f(s1, s2, x);
  float n3 = __builtin_amdgcn_fmed3f(s2, s3, x);
  i2 = c1 ? i1 : (c2 ? ix : i2);
  i1 = c1 ? ix : i1;
  s1 = fminf(s1, x);
  s2 = n2;
  s3 = n3;
}

// ---------------- top-3 butterfly merge across 16-lane groups ----------------
__device__ __forceinline__ void merge3(float& a1, float& ai1, float& a2,
                                       float& ai2, float& a3, int off) {
  float b1  = __shfl_xor(a1, off, 64);
  float bi1 = __shfl_xor(ai1, off, 64);
  float b2  = __shfl_xor(a2, off, 64);
  float bi2 = __shfl_xor(ai2, off, 64);
  float b3  = __shfl_xor(a3, off, 64);
  bool f1 = a1 <= b1;
  float m1  = f1 ? a1 : b1;
  float mi1 = f1 ? ai1 : bi1;
  float hi  = f1 ? b1 : a1;
  float hii = f1 ? bi1 : ai1;
  bool f2 = a2 <= b2;
  float c2  = f2 ? a2 : b2;
  float ci2 = f2 ? ai2 : bi2;
  bool f3 = hi <= c2;
  float m2  = f3 ? hi : c2;
  float mi2 = f3 ? hii : ci2;
  float m3  = fminf(fmaxf(hi, c2), fminf(a3, b3));
  a1 = m1; ai1 = mi1; a2 = m2; ai2 = mi2; a3 = m3;
}

// ---------------- K1: MFMA distances, 128 pts/block, double-buffered E ----------------
__global__ __launch_bounds__(256, 2) void k_assign_mfma(
    const float* __restrict__ Z, const unsigned short* __restrict__ ehi_g,
    const unsigned short* __restrict__ elo_g, const float* __restrict__ esq_g,
    float* __restrict__ part) {
  // [0,32K): E buf0 (hi 16K, lo 16K); [32K,64K): E buf1 / z-staging alias;
  // [64K,68K): esq (1024 f32)
  __shared__ __align__(16) char smem[69632];
  float* esq_s = reinterpret_cast<float*>(smem + 65536);

  const int tid  = threadIdx.x;
  const int lane = tid & 63;
  const int wv   = tid >> 6;
  const int bb   = blockIdx.x * 128;
  const int img  = bb >> 12;
  const int pix0 = bb & 4095;

  // ---- stage esq (whole table, once) ----
#pragma unroll
  for (int r = 0; r < 4; ++r) esq_s[r * 256 + tid] = esq_g[r * 256 + tid];

  // ---- stage z into buf1 region: split bf16 hi/lo, swizzled ----
  {
    const int pt = tid & 127;
    const int grp = tid >> 7;                 // 0/1: dims 0-31 / 32-63
    const int gb = img * BSTRIDE + pix0 + pt;
    unsigned* zh32 = reinterpret_cast<unsigned*>(smem + 32768);
    unsigned* zl32 = reinterpret_cast<unsigned*>(smem + 49152);
    const int sw = (pt & 7) << 3;
#pragma unroll
    for (int it = 0; it < 16; ++it) {
      int k0 = (grp * 16 + it) * 2;
      float v0 = Z[gb + k0 * HW];
      float v1 = Z[gb + (k0 + 1) * HW];
      unsigned short h0 = f2bf_rne(v0);
      unsigned short h1 = f2bf_rne(v1);
      unsigned short l0 = f2bf_rne(v0 - bf2f(h0));
      unsigned short l1 = f2bf_rne(v1 - bf2f(h1));
      int ui = pt * 32 + ((k0 ^ sw) >> 1);
      zh32[ui] = (unsigned)h0 | ((unsigned)h1 << 16);
      zl32[ui] = (unsigned)l0 | ((unsigned)l1 << 16);
    }
  }
  __syncthreads();

#define STAGE_E(bsel, chk)                                                     \
  {                                                                            \
    _Pragma("unroll")                                                          \
    for (int r = 0; r < 4; ++r) {                                              \
      int go = (chk) * 16384 + (r * 256 + tid) * 16;                           \
      int lo_ = (bsel) * 32768 + (r * 256 + tid) * 16;                         \
      __builtin_amdgcn_global_load_lds(                                        \
          (const __attribute__((address_space(1))) float*)                     \
              (reinterpret_cast<const char*>(ehi_g) + go),                     \
          (__attribute__((address_space(3))) float*)(smem + lo_), 16, 0, 0);   \
      __builtin_amdgcn_global_load_lds(                                        \
          (const __attribute__((address_space(1))) float*)                     \
              (reinterpret_cast<const char*>(elo_g) + go),                     \
          (__attribute__((address_space(3))) float*)(smem + lo_ + 16384),      \
          16, 0, 0);                                                           \
    }                                                                          \
  }

  // issue chunk-0 stage early, overlap with A-frag LDS reads
  STAGE_E(0, 0);

  // ---- load A fragments (z) from buf1 region ----
  const int col = lane & 15;
  const int g16 = (lane >> 4) * 16;
  bf16x8 a0h0, a0h1, a0l0, a0l1, a1h0, a1h1, a1l0, a1l1;
  {
    const char* zhb = smem + 32768;
    const char* zlb = smem + 49152;
    int pt0 = wv * 32 + col;
    int pt1 = pt0 + 16;
    int sw0 = (pt0 & 7) << 4, sw1 = (pt1 & 7) << 4;
    a0h0 = *reinterpret_cast<const bf16x8*>(zhb + pt0 * 128 + (g16 ^ sw0));
    a0h1 = *reinterpret_cast<const bf16x8*>(zhb + pt0 * 128 + ((64 + g16) ^ sw0));
    a0l0 = *reinterpret_cast<const bf16x8*>(zlb + pt0 * 128 + (g16 ^ sw0));
    a0l1 = *reinterpret_cast<const bf16x8*>(zlb + pt0 * 128 + ((64 + g16) ^ sw0));
    a1h0 = *reinterpret_cast<const bf16x8*>(zhb + pt1 * 128 + (g16 ^ sw1));
    a1h1 = *reinterpret_cast<const bf16x8*>(zhb + pt1 * 128 + ((64 + g16) ^ sw1));
    a1l0 = *reinterpret_cast<const bf16x8*>(zlb + pt1 * 128 + (g16 ^ sw1));
    a1l1 = *reinterpret_cast<const bf16x8*>(zlb + pt1 * 128 + ((64 + g16) ^ sw1));
  }
  __syncthreads();  // chunk0 staged; z no longer needed in LDS

  // ---- per-lane running top-3 state ----
  float s1a[2][4], s2a[2][4], s3a[2][4], i1a[2][4], i2a[2][4];
#pragma unroll
  for (int rt = 0; rt < 2; ++rt)
#pragma unroll
    for (int j = 0; j < 4; ++j) {
      s1a[rt][j] = 3.4e38f; s2a[rt][j] = 3.4e38f; s3a[rt][j] = 3.4e38f;
      i1a[rt][j] = 0.f; i2a[rt][j] = 0.f;
    }

  const int swc = (col & 7) << 4;

  for (int chunk = 0; chunk < 8; ++chunk) {
    const int cur = chunk & 1;
    if (chunk < 7) STAGE_E(cur ^ 1, chunk + 1);
    const char* ehb = smem + cur * 32768;
    const char* elb = ehb + 16384;

    for (int ct = 0; ct < 8; ++ct) {
      const int cl = ct * 16 + col;
      bf16x8 bh0 = *reinterpret_cast<const bf16x8*>(ehb + cl * 128 + (g16 ^ swc));
      bf16x8 bh1 = *reinterpret_cast<const bf16x8*>(ehb + cl * 128 + ((64 + g16) ^ swc));
      bf16x8 bl0 = *reinterpret_cast<const bf16x8*>(elb + cl * 128 + (g16 ^ swc));
      bf16x8 bl1 = *reinterpret_cast<const bf16x8*>(elb + cl * 128 + ((64 + g16) ^ swc));
      float half_esq = 0.5f * esq_s[chunk * 128 + cl];
      float fcode = (float)(chunk * 128 + cl);

      f32x4 acc0 = {0.f, 0.f, 0.f, 0.f};
      f32x4 acc1 = {0.f, 0.f, 0.f, 0.f};
      acc0 = __builtin_amdgcn_mfma_f32_16x16x32_bf16(a0h0, bh0, acc0, 0, 0, 0);
      acc1 = __builtin_amdgcn_mfma_f32_16x16x32_bf16(a1h0, bh0, acc1, 0, 0, 0);
      acc0 = __builtin_amdgcn_mfma_f32_16x16x32_bf16(a0h1, bh1, acc0, 0, 0, 0);
      acc1 = __builtin_amdgcn_mfma_f32_16x16x32_bf16(a1h1, bh1, acc1, 0, 0, 0);
      acc0 = __builtin_amdgcn_mfma_f32_16x16x32_bf16(a0h0, bl0, acc0, 0, 0, 0);
      acc1 = __builtin_amdgcn_mfma_f32_16x16x32_bf16(a1h0, bl0, acc1, 0, 0, 0);
      acc0 = __builtin_amdgcn_mfma_f32_16x16x32_bf16(a0h1, bl1, acc0, 0, 0, 0);
      acc1 = __builtin_amdgcn_mfma_f32_16x16x32_bf16(a1h1, bl1, acc1, 0, 0, 0);
      acc0 = __builtin_amdgcn_mfma_f32_16x16x32_bf16(a0l0, bh0, acc0, 0, 0, 0);
      acc1 = __builtin_amdgcn_mfma_f32_16x16x32_bf16(a1l0, bh0, acc1, 0, 0, 0);
      acc0 = __builtin_amdgcn_mfma_f32_16x16x32_bf16(a0l1, bh1, acc0, 0, 0, 0);
      acc1 = __builtin_amdgcn_mfma_f32_16x16x32_bf16(a1l1, bh1, acc1, 0, 0, 0);

#pragma unroll
      for (int j = 0; j < 4; ++j)
        ins3(half_esq - acc0[j], fcode, s1a[0][j], s2a[0][j], s3a[0][j],
             i1a[0][j], i2a[0][j]);
#pragma unroll
      for (int j = 0; j < 4; ++j)
        ins3(half_esq - acc1[j], fcode, s1a[1][j], s2a[1][j], s3a[1][j],
             i1a[1][j], i2a[1][j]);
    }
    __syncthreads();  // next buffer staged; this buffer free for chunk+2
  }
#undef STAGE_E

  // ---- merge across the 16 lanes holding each point; write top-3 ----
  const int g = lane >> 4;
  float* ps1 = part;
  float* pi1 = part + N_PTS;
  float* ps2 = part + 2 * N_PTS;
  float* pi2 = part + 3 * N_PTS;
  float* ps3 = part + 4 * N_PTS;
#pragma unroll
  for (int rt = 0; rt < 2; ++rt)
#pragma unroll
    for (int j = 0; j < 4; ++j) {
      float v1 = s1a[rt][j], w1i = i1a[rt][j];
      float v2 = s2a[rt][j], w2i = i2a[rt][j];
      float v3 = s3a[rt][j];
      merge3(v1, w1i, v2, w2i, v3, 1);
      merge3(v1, w1i, v2, w2i, v3, 2);
      merge3(v1, w1i, v2, w2i, v3, 4);
      merge3(v1, w1i, v2, w2i, v3, 8);
      if ((lane & 15) == j) {
        int n = bb + wv * 32 + rt * 16 + g * 4 + j;
        ps1[n] = v1; pi1[n] = w1i; ps2[n] = v2; pi2[n] = w2i; ps3[n] = v3;
      }
    }
}

// ---------------- K2: finalize, tie-resolve, gather/eq/loss, zt ----------------
__global__ __launch_bounds__(256) void k_combine(
    const float* __restrict__ Z, const float* __restrict__ E,
    const float* __restrict__ part,
    float* __restrict__ eq_out, float* __restrict__ idx_out,
    float* __restrict__ counts, float* __restrict__ loss_acc,
    float* __restrict__ zt) {
  __shared__ float lred[4];
  const int n = blockIdx.x * 256 + threadIdx.x;
  const int zbase = (n >> 12) * BSTRIDE + (n & 4095);

  float zr[64];
#pragma unroll
  for (int d = 0; d < 64; ++d) zr[d] = Z[zbase + d * HW];
  float zsq = 0.f;
#pragma unroll
  for (int d = 0; d < 64; ++d) zsq = fmaf(zr[d], zr[d], zsq);

  float w1 = zsq + 2.f * part[n];
  int i1g = (int)part[N_PTS + n];
  float w2 = zsq + 2.f * part[2 * N_PTS + n];
  int i2g = (int)part[3 * N_PTS + n];
  float w3 = zsq + 2.f * part[4 * N_PTS + n];

  if (zt) {
    float4* zt4 = reinterpret_cast<float4*>(zt + (size_t)n * 64);
#pragma unroll
    for (int j = 0; j < 16; ++j)
      zt4[j] = make_float4(zr[4 * j + 0], zr[4 * j + 1], zr[4 * j + 2], zr[4 * j + 3]);
  }

  int bi = i1g;
  if (w3 - w1 < MX_FULL) {
    double b = 1e300; int bb = 0;
    for (int c = 0; c < K_CODES; ++c) {
      const float* ep = E + c * D_DIM;
      double s = 0.0;
      for (int d = 0; d < 64; ++d) {
        double v = (double)zr[d] - (double)ep[d];
        s += v * v;
      }
      if (s < b) { b = s; bb = c; }
    }
    bi = bb;
  } else if (w2 - w1 < MX_RESCORE) {
    const float* ea = E + i1g * D_DIM;
    const float* eb = E + i2g * D_DIM;
    double da = 0.0, db = 0.0;
#pragma unroll
    for (int d = 0; d < 64; ++d) {
      double va = (double)zr[d] - (double)ea[d]; da += va * va;
      double vb = (double)zr[d] - (double)eb[d]; db += vb * vb;
    }
    if (db < da || (db == da && i2g < i1g)) bi = i2g;
  }

  idx_out[n] = (float)bi;
  atomicAdd(&counts[bi], 1.0f);

  const float4* er = reinterpret_cast<const float4*>(E + bi * D_DIM);
  float lsum = 0.f;
#pragma unroll
  for (int j = 0; j < 16; ++j) {
    float4 ev = er[j];
    int d = 4 * j;
    eq_out[zbase + (d + 0) * HW] = ev.x;
    eq_out[zbase + (d + 1) * HW] = ev.y;
    eq_out[zbase + (d + 2) * HW] = ev.z;
    eq_out[zbase + (d + 3) * HW] = ev.w;
    float f0 = ev.x - zr[d + 0], f1 = ev.y - zr[d + 1];
    float f2 = ev.z - zr[d + 2], f3 = ev.w - zr[d + 3];
    lsum = fmaf(f0, f0, lsum); lsum = fmaf(f1, f1, lsum);
    lsum = fmaf(f2, f2, lsum); lsum = fmaf(f3, f3, lsum);
  }
#pragma unroll
  for (int off = 32; off >= 1; off >>= 1) lsum += __shfl_xor(lsum, off, 64);
  int lane = threadIdx.x & 63, wid = threadIdx.x >> 6;
  if (lane == 0) lred[wid] = lsum;
  __syncthreads();
  if (threadIdx.x == 0)
    atomicAdd(loss_acc, lred[0] + lred[1] + lred[2] + lred[3]);
}

// ---------------- fallback: single-pass fp32 assign (if ws too small) ----------------
__global__ __launch_bounds__(256) void k_solo(
    const float* __restrict__ Z, const float* __restrict__ E,
    const float* __restrict__ esq,
    float* __restrict__ eq_out, float* __restrict__ idx_out,
    float* __restrict__ counts, float* __restrict__ loss_acc) {
  __shared__ float sE[CHUNK * D_DIM];
  __shared__ float sQ[CHUNK];
  int n = blockIdx.x * 256 + threadIdx.x;
  int zbase = (n >> 12) * BSTRIDE + (n & 4095);

  float zr[64];
#pragma unroll
  for (int d = 0; d < 64; ++d) zr[d] = Z[zbase + d * HW];
  float zsq = 0.f;
#pragma unroll
  for (int d = 0; d < 64; ++d) zsq = fmaf(zr[d], zr[d], zsq);

  float b1 = 3.4e38f, b2 = 3.4e38f, b3 = 3.4e38f;
  int i1 = 0, i2 = 0;
  for (int ch = 0; ch < K_CODES / CHUNK; ++ch) {
    __syncthreads();
    const float4* src = reinterpret_cast<const float4*>(E + ch * CHUNK * D_DIM);
    float4* dst = reinterpret_cast<float4*>(sE);
#pragma unroll
    for (int j = 0; j < 8; ++j) dst[threadIdx.x + 256 * j] = src[threadIdx.x + 256 * j];
    if (threadIdx.x < CHUNK) sQ[threadIdx.x] = esq[ch * CHUNK + threadIdx.x];
    __syncthreads();
    for (int c = 0; c < CHUNK; ++c) {
      const float4* ep = reinterpret_cast<const float4*>(sE + c * D_DIM);
      float d0 = 0.f, d1 = 0.f, d2 = 0.f, d3 = 0.f;
#pragma unroll
      for (int j = 0; j < 16; ++j) {
        float4 v = ep[j];
        d0 = fmaf(zr[4 * j + 0], v.x, d0);
        d1 = fmaf(zr[4 * j + 1], v.y, d1);
        d2 = fmaf(zr[4 * j + 2], v.z, d2);
        d3 = fmaf(zr[4 * j + 3], v.w, d3);
      }
      float dist = zsq + sQ[c] - 2.f * ((d0 + d1) + (d2 + d3));
      int cg = ch * CHUNK + c;
      bool lt1 = dist < b1, lt2 = dist < b2, lt3 = dist < b3;
      b3 = lt2 ? b2 : (lt3 ? dist : b3);
      b2 = lt1 ? b1 : (lt2 ? dist : b2);
      i2 = lt1 ? i1 : (lt2 ? cg : i2);
      b1 = lt1 ? dist : b1;
      i1 = lt1 ? cg : i1;
    }
  }
  int bi = i1;
  if (b3 - b1 < M_FULL) {
    double b = 1e300; int bb = 0;
    for (int c = 0; c < K_CODES; ++c) {
      const float* ep = E + c * D_DIM;
      double s = 0.0;
      for (int d = 0; d < 64; ++d) { double v = (double)zr[d] - (double)ep[d]; s += v * v; }
      if (s < b) { b = s; bb = c; }
    }
    bi = bb;
  } else if (b2 - b1 < M_RESCORE) {
    const float* ea = E + i1 * D_DIM;
    const float* eb = E + i2 * D_DIM;
    double da = 0.0, db = 0.0;
#pragma unroll
    for (int d = 0; d < 64; ++d) {
      double va = (double)zr[d] - (double)ea[d]; da += va * va;
      double vb = (double)zr[d] - (double)eb[d]; db += vb * vb;
    }
    if (db < da || (db == da && i2 < i1)) bi = i2;
  }

  idx_out[n] = (float)bi;
  atomicAdd(&counts[bi], 1.0f);
  const float4* er = reinterpret_cast<const float4*>(E + bi * D_DIM);
  float lsum = 0.f;
#pragma unroll
  for (int j = 0; j < 16; ++j) {
    float4 ev = er[j];
    int d = 4 * j;
    eq_out[zbase + (d + 0) * HW] = ev.x;
    eq_out[zbase + (d + 1) * HW] = ev.y;
    eq_out[zbase + (d + 2) * HW] = ev.z;
    eq_out[zbase + (d + 3) * HW] = ev.w;
    float f0 = ev.x - zr[d + 0], f1 = ev.y - zr[d + 1];
    float f2 = ev.z - zr[d + 2], f3 = ev.w - zr[d + 3];
    lsum = fmaf(f0, f0, lsum); lsum = fmaf(f1, f1, lsum);
    lsum = fmaf(f2, f2, lsum); lsum = fmaf(f3, f3, lsum);
  }
#pragma unroll
  for (int off = 32; off >= 1; off >>= 1) lsum += __shfl_xor(lsum, off, 64);
  if ((threadIdx.x & 63) == 0) atomicAdd(loss_acc, lsum);
}

// ---------------- K3: stats, smoothing scalars, threefry, prefix-sum ----------------
__global__ __launch_bounds__(1024) void k_stats(
    const float* __restrict__ counts, const float* __restrict__ cluster_size,
    float* __restrict__ out, float* __restrict__ ws,
    unsigned* __restrict__ rnd, const float* __restrict__ loss_acc,
    int* __restrict__ basep, int* __restrict__ cursorp) {
  __shared__ float red[16][4];
  __shared__ int sc[1024];
  int c = threadIdx.x;
  float cnt = counts[c];
  float csb = cluster_size[c] * 0.99f + cnt * 0.01f;
  out[OFF_CSB + c] = csb;

  float v_n = csb;
  float v_s = csb + 1e-5f;
  float p = cnt * (1.0f / 65536.0f);
  float v_p = p * logf(p + 1e-10f);
  float v_u = cnt > 0.f ? 1.f : 0.f;
#pragma unroll
  for (int off = 32; off >= 1; off >>= 1) {
    v_n += __shfl_xor(v_n, off, 64);
    v_s += __shfl_xor(v_s, off, 64);
    v_p += __shfl_xor(v_p, off, 64);
    v_u += __shfl_xor(v_u, off, 64);
  }
  int lane = threadIdx.x & 63, wid = threadIdx.x >> 6;
  if (lane == 0) { red[wid][0] = v_n; red[wid][1] = v_s; red[wid][2] = v_p; red[wid][3] = v_u; }
  __syncthreads();
  if (threadIdx.x == 0) {
    float nsum = 0.f, ssum = 0.f, psum = 0.f, usum = 0.f;
    for (int w = 0; w < 16; ++w) {
      nsum += red[w][0]; ssum += red[w][1]; psum += red[w][2]; usum += red[w][3];
    }
    ws[WS_NVAL] = nsum;
    ws[WS_SCS]  = ssum;
    out[OFF_STATS + 0] = expf(-psum);
    out[OFF_STATS + 1] = usum;
    out[OFF_LOSS] = 1.25f * loss_acc[0] * (1.0f / 4194304.0f);
  }
  rnd[c] = tf_rand_bits(c) & 0xFFFFu;

  if (basep) {
    // exclusive prefix sum of counts -> base / cursor
    int ci = (int)cnt;
    sc[c] = ci;
    __syncthreads();
    for (int off = 1; off < 1024; off <<= 1) {
      int v = (c >= off) ? sc[c - off] : 0;
      __syncthreads();
      sc[c] += v;
      __syncthreads();
    }
    int b = sc[c] - ci;
    basep[c] = b;
    cursorp[c] = b;
    if (c == 1023) basep[1024] = sc[1023];
  }
}

// ---------------- K3b: counting-sort scatter ----------------
__global__ __launch_bounds__(256) void k_scatter(
    const float* __restrict__ idxf, int* __restrict__ cursor,
    int* __restrict__ sorted) {
  int n = blockIdx.x * 256 + threadIdx.x;
  int bi = (int)idxf[n];
  int pos = atomicAdd(&cursor[bi], 1);
  sorted[pos] = n;
}

// ---------------- K4: bucket-gather embed_sum + EMA + embedding ----------------
__global__ __launch_bounds__(256) void k_update3(
    const float* __restrict__ zt, const float* __restrict__ embed_avg,
    const float* __restrict__ ws, const int* __restrict__ base,
    const int* __restrict__ sorted, const unsigned* __restrict__ rnd,
    float* __restrict__ out) {
  __shared__ float sm[4][64];
  const int c = blockIdx.x;
  const int d = threadIdx.x & 63, w = threadIdx.x >> 6;
  const int s0 = base[c], e0 = base[c + 1];
  float es = 0.f;
  for (int i = s0 + w; i < e0; i += 4) {
    int id = sorted[i];
    es += zt[(size_t)id * 64 + d];
  }
  sm[w][d] = es;
  __syncthreads();
  if (w == 0) {
    es = ((sm[0][d] + sm[1][d]) + sm[2][d]) + sm[3][d];
    float csb = out[OFF_CSB + c];
    float nval = ws[WS_NVAL], scs = ws[WS_SCS];
    float cs = (csb + 1e-5f) / fmaxf(scs, 1e-8f) * nval;
    bool dead = cs < 1.0f;
    float csf = dead ? 1.0f : cs;
    float ea_ema = embed_avg[c * D_DIM + d] * 0.99f + es * 0.01f;
    int r = (int)rnd[c];
    float zv = zt[(size_t)r * 64 + d];
    float ea = dead ? zv : ea_ema;
    out[OFF_EAB + c * D_DIM + d] = ea;
    out[OFF_EMB + c * D_DIM + d] = ea / csf;
  }
}

// ---------------- K4 slow fallback: strided Z gather ----------------
__global__ __launch_bounds__(64) void k_update_slow(
    const float* __restrict__ Z, const float* __restrict__ embed_avg,
    const float* __restrict__ ws, const unsigned* __restrict__ rnd,
    const float* __restrict__ idxf, float* __restrict__ out) {
  const int c = blockIdx.x, d = threadIdx.x;
  const float cf = (float)c;
  float es = 0.f;
  const float4* i4 = reinterpret_cast<const float4*>(idxf);
  float4 cur = i4[d];
  for (int it = 0; it < 256; ++it) {
    float4 nxt = cur;
    if (it < 255) nxt = i4[(it + 1) * 64 + d];
    unsigned long long m0 = __ballot(cur.x == cf);
    unsigned long long m1 = __ballot(cur.y == cf);
    unsigned long long m2 = __ballot(cur.z == cf);
    unsigned long long m3 = __ballot(cur.w == cf);
    while (m0) { int b = __ffsll(m0) - 1; m0 &= m0 - 1;
      int p = it * 256 + b * 4 + 0; es += Z[(p >> 12) * BSTRIDE + d * HW + (p & 4095)]; }
    while (m1) { int b = __ffsll(m1) - 1; m1 &= m1 - 1;
      int p = it * 256 + b * 4 + 1; es += Z[(p >> 12) * BSTRIDE + d * HW + (p & 4095)]; }
    while (m2) { int b = __ffsll(m2) - 1; m2 &= m2 - 1;
      int p = it * 256 + b * 4 + 2; es += Z[(p >> 12) * BSTRIDE + d * HW + (p & 4095)]; }
    while (m3) { int b = __ffsll(m3) - 1; m3 &= m3 - 1;
      int p = it * 256 + b * 4 + 3; es += Z[(p >> 12) * BSTRIDE + d * HW + (p & 4095)]; }
    cur = nxt;
  }
  float csb = out[OFF_CSB + c];
  float nval = ws[WS_NVAL], scs = ws[WS_SCS];
  float cs = (csb + 1e-5f) / fmaxf(scs, 1e-8f) * nval;
  bool dead = cs < 1.0f;
  float csf = dead ? 1.0f : cs;
  float ea_ema = embed_avg[c * D_DIM + d] * 0.99f + es * 0.01f;
  int r = (int)rnd[c];
  float zv = Z[(r >> 12) * BSTRIDE + d * HW + (r & 4095)];
  float ea = dead ? zv : ea_ema;
  out[OFF_EAB + c * D_DIM + d] = ea;
  out[OFF_EMB + c * D_DIM + d] = ea / csf;
}

extern "C" void kernel_launch(void* const* d_in, const int* in_sizes, int n_in,
                              void* d_out, int out_size, void* d_ws, size_t ws_size,
                              hipStream_t stream) {
  const float* Z  = (const float*)d_in[0];
  const float* E  = (const float*)d_in[1];
  const float* CS = (const float*)d_in[2];
  const float* EA = (const float*)d_in[3];
  float* out = (float*)d_out;
  float* ws  = (float*)d_ws;
  unsigned* rnd = (unsigned*)(ws + WS_RAND);

  const size_t need = (size_t)(WS_ZT + (size_t)N_PTS * D_DIM + 16) * sizeof(float);
  const bool big = ws_size >= need;

  hipMemsetAsync(ws, 0, 1028 * sizeof(float), stream);
  k_esq<<<4, 256, 0, stream>>>(E, ws + WS_ESQ);
  if (big) {
    unsigned short* ehi = (unsigned short*)(ws + WS_EHI);
    unsigned short* elo = (unsigned short*)(ws + WS_ELO);
    int* basep   = (int*)(ws + WS_BASE);
    int* cursorp = (int*)(ws + WS_CURS);
    int* sorted  = (int*)(ws + WS_SORT);
    float* zt = ws + WS_ZT;
    k_cvt<<<256, 256, 0, stream>>>(E, ehi, elo);
    k_assign_mfma<<<N_PTS / 128, 256, 0, stream>>>(Z, ehi, elo, ws + WS_ESQ, ws + WS_PART);
    k_combine<<<N_PTS / 256, 256, 0, stream>>>(Z, E, ws + WS_PART,
                                               out + OFF_EQ, out + OFF_IDX,
                                               ws + WS_CNT, ws + WS_LOSS, zt);
    k_stats<<<1, 1024, 0, stream>>>(ws + WS_CNT, CS, out, ws, rnd, ws + WS_LOSS,
                                    basep, cursorp);
    k_scatter<<<N_PTS / 256, 256, 0, stream>>>(out + OFF_IDX, cursorp, sorted);
    k_update3<<<K_CODES, 256, 0, stream>>>(zt, EA, ws, basep, sorted, rnd, out);
  } else {
    k_solo<<<N_PTS / 256, 256, 0, stream>>>(Z, E, ws + WS_ESQ,
                                            out + OFF_EQ, out + OFF_IDX,
                                            ws + WS_CNT, ws + WS_LOSS);
    k_stats<<<1, 1024, 0, stream>>>(ws + WS_CNT, CS, out, ws, rnd, ws + WS_LOSS,
                                    (int*)nullptr, (int*)nullptr);
    k_update_slow<<<K_CODES, 64, 0, stream>>>(Z, EA, ws, rnd, out + OFF_IDX, out);
  }
}

// Round 7
// 135.916 us; speedup vs baseline: 1.5302x; 1.5302x over previous
//
#include <hip/hip_runtime.h>
#include <math.h>

#define K_CODES 1024
#define D_DIM   64
#define N_PTS   65536
#define HW      4096
#define BSTRIDE 262144   // 64*4096 elements per batch image
#define CHUNK   128

// output offsets (floats)
#define OFF_EQ    0
#define OFF_IDX   4194304
#define OFF_LOSS  4259840
#define OFF_STATS 4259841
#define OFF_EMB   4259843
#define OFF_CSB   4325379
#define OFF_EAB   4326403

// workspace layout (float slots)
#define WS_LOSS 0
#define WS_NVAL 1
#define WS_SCS  2
#define WS_CNT  4
#define WS_ESQ  1028
#define WS_RAND 2052
#define WS_EHI  3076                   // 65536 ushort, swizzled bf16-hi (dead after assign)
#define WS_ELO  35844                  // 65536 ushort, swizzled bf16-lo (dead after assign)
#define WS_ESUM WS_EHI                 // float[65536] = 256KB, overlays EHI+ELO after assign
#define WS_PART 68612                  // 5 arrays of N: s1,i1,s2,i2,s3
#define WS_SORT WS_PART                // int[N] packed (code<<16|n), overlays part after combine
#define WS_BASE (WS_PART + N_PTS)      // int[1025], overlays part s2 (dead after combine)
#define WS_CURS (WS_PART + N_PTS + 1040) // int[1024]
#define WS_ZT   (WS_PART + 5 * N_PTS)  // transposed z: [N][64]

// fp32-exact fallback thresholds
#define M_RESCORE 0.01f
#define M_FULL    5e-4f
// MFMA-approx thresholds (dist error bound ~3e-3)
#define MX_RESCORE 0.05f
#define MX_FULL    8e-3f

typedef __attribute__((ext_vector_type(8))) __bf16 bf16x8;
typedef __attribute__((ext_vector_type(4))) float  f32x4;

// ---------------- bf16 split helpers ----------------
__device__ __forceinline__ unsigned short f2bf_rne(float x) {
  unsigned u = __float_as_uint(x);
  unsigned r = u + 0x7FFFu + ((u >> 16) & 1u);
  return (unsigned short)(r >> 16);
}
__device__ __forceinline__ float bf2f(unsigned short h) {
  return __uint_as_float(((unsigned)h) << 16);
}

// ---------------- threefry2x32 (JAX-compatible) ----------------
__device__ __forceinline__ void tf_block(unsigned k0, unsigned k1,
                                         unsigned& x0, unsigned& x1) {
  unsigned ks2 = k0 ^ k1 ^ 0x1BD11BDAu;
  x0 += k0; x1 += k1;
#define RR(r) { x0 += x1; x1 = (x1 << r) | (x1 >> (32 - r)); x1 ^= x0; }
  RR(13) RR(15) RR(26) RR(6)
  x0 += k1; x1 += ks2 + 1u;
  RR(17) RR(29) RR(16) RR(24)
  x0 += ks2; x1 += k0 + 2u;
  RR(13) RR(15) RR(26) RR(6)
  x0 += k0; x1 += k1 + 3u;
  RR(17) RR(29) RR(16) RR(24)
  x0 += k1; x1 += ks2 + 4u;
  RR(13) RR(15) RR(26) RR(6)
  x0 += ks2; x1 += k0 + 5u;
#undef RR
}

__device__ __forceinline__ unsigned tf_rand_bits(int c) {
  unsigned a0 = 0u, a1 = 2u; tf_block(0u, 1u, a0, a1);
  unsigned b0 = 1u, b1 = 3u; tf_block(0u, 1u, b0, b1);
  unsigned K0 = a1, K1 = b1;
  unsigned x0, x1;
  if (c < 512) { x0 = (unsigned)c; x1 = (unsigned)(512 + c); tf_block(K0, K1, x0, x1); return x0; }
  else         { x0 = (unsigned)(c - 512); x1 = (unsigned)c; tf_block(K0, K1, x0, x1); return x1; }
}

// ---------------- K0 (fallback path): codebook squared norms ----------------
__global__ void k_esq(const float* __restrict__ E, float* __restrict__ esq) {
  int c = blockIdx.x * blockDim.x + threadIdx.x;
  if (c >= K_CODES) return;
  const float4* e4 = reinterpret_cast<const float4*>(E + c * D_DIM);
  float s = 0.f;
#pragma unroll
  for (int j = 0; j < 16; ++j) {
    float4 v = e4[j];
    s += v.x * v.x + v.y * v.y + v.z * v.z + v.w * v.w;
  }
  esq[c] = s;
}

// ---------------- K0' (big path): fused esq + swizzled bf16 hi/lo split ----------------
__global__ __launch_bounds__(256) void k_prep(const float* __restrict__ E,
                                              float* __restrict__ esq,
                                              unsigned short* __restrict__ ehi,
                                              unsigned short* __restrict__ elo) {
  int idx = blockIdx.x * 256 + threadIdx.x;  // 0..65535; one wave == one code
  int c = idx >> 6, k = idx & 63;
  float v = E[idx];
  unsigned short h = f2bf_rne(v);
  unsigned short l = f2bf_rne(v - bf2f(h));
  int pos = (c << 6) | (k ^ ((c & 7) << 3));  // XOR-swizzle (16B granules)
  ehi[pos] = h;
  elo[pos] = l;
  float s = v * v;
#pragma unroll
  for (int off = 32; off >= 1; off >>= 1) s += __shfl_xor(s, off, 64);
  if (k == 0) esq[c] = s;
}

// ---------------- top-3 insert ----------------
__device__ __forceinline__ void ins3(float x, float ix, float& s1, float& s2,
                                     float& s3, float& i1, float& i2) {
  bool c1 = x < s1;
  bool c2 = x < s2;
  float n2 = __builtin_amdgcn_fmed3f(s1, s2, x);
  float n3 = __builtin_amdgcn_fmed3f(s2, s3, x);
  i2 = c1 ? i1 : (c2 ? ix : i2);
  i1 = c1 ? ix : i1;
  s1 = fminf(s1, x);
  s2 = n2;
  s3 = n3;
}

// ---------------- top-3 butterfly merge across 16-lane groups ----------------
__device__ __forceinline__ void merge3(float& a1, float& ai1, float& a2,
                                       float& ai2, float& a3, int off) {
  float b1  = __shfl_xor(a1, off, 64);
  float bi1 = __shfl_xor(ai1, off, 64);
  float b2  = __shfl_xor(a2, off, 64);
  float bi2 = __shfl_xor(ai2, off, 64);
  float b3  = __shfl_xor(a3, off, 64);
  bool f1 = a1 <= b1;
  float m1  = f1 ? a1 : b1;
  float mi1 = f1 ? ai1 : bi1;
  float hi  = f1 ? b1 : a1;
  float hii = f1 ? bi1 : ai1;
  bool f2 = a2 <= b2;
  float c2  = f2 ? a2 : b2;
  float ci2 = f2 ? ai2 : bi2;
  bool f3 = hi <= c2;
  float m2  = f3 ? hi : c2;
  float mi2 = f3 ? hii : ci2;
  float m3  = fminf(fmaxf(hi, c2), fminf(a3, b3));
  a1 = m1; ai1 = mi1; a2 = m2; ai2 = mi2; a3 = m3;
}

// ---------------- K1: MFMA distances, 128 pts/block, double-buffered E ----------------
__global__ __launch_bounds__(256, 2) void k_assign_mfma(
    const float* __restrict__ Z, const unsigned short* __restrict__ ehi_g,
    const unsigned short* __restrict__ elo_g, const float* __restrict__ esq_g,
    float* __restrict__ part) {
  __shared__ __align__(16) char smem[69632];
  float* esq_s = reinterpret_cast<float*>(smem + 65536);

  const int tid  = threadIdx.x;
  const int lane = tid & 63;
  const int wv   = tid >> 6;
  const int bb   = blockIdx.x * 128;
  const int img  = bb >> 12;
  const int pix0 = bb & 4095;

#pragma unroll
  for (int r = 0; r < 4; ++r) esq_s[r * 256 + tid] = esq_g[r * 256 + tid];

  // ---- stage z into buf1 region: split bf16 hi/lo, swizzled ----
  {
    const int pt = tid & 127;
    const int grp = tid >> 7;
    const int gb = img * BSTRIDE + pix0 + pt;
    unsigned* zh32 = reinterpret_cast<unsigned*>(smem + 32768);
    unsigned* zl32 = reinterpret_cast<unsigned*>(smem + 49152);
    const int sw = (pt & 7) << 3;
#pragma unroll
    for (int it = 0; it < 16; ++it) {
      int k0 = (grp * 16 + it) * 2;
      float v0 = Z[gb + k0 * HW];
      float v1 = Z[gb + (k0 + 1) * HW];
      unsigned short h0 = f2bf_rne(v0);
      unsigned short h1 = f2bf_rne(v1);
      unsigned short l0 = f2bf_rne(v0 - bf2f(h0));
      unsigned short l1 = f2bf_rne(v1 - bf2f(h1));
      int ui = pt * 32 + ((k0 ^ sw) >> 1);
      zh32[ui] = (unsigned)h0 | ((unsigned)h1 << 16);
      zl32[ui] = (unsigned)l0 | ((unsigned)l1 << 16);
    }
  }
  __syncthreads();

#define STAGE_E(bsel, chk)                                                     \
  {                                                                            \
    _Pragma("unroll")                                                          \
    for (int r = 0; r < 4; ++r) {                                              \
      int go = (chk) * 16384 + (r * 256 + tid) * 16;                           \
      int lo_ = (bsel) * 32768 + (r * 256 + tid) * 16;                         \
      __builtin_amdgcn_global_load_lds(                                        \
          (const __attribute__((address_space(1))) float*)                     \
              (reinterpret_cast<const char*>(ehi_g) + go),                     \
          (__attribute__((address_space(3))) float*)(smem + lo_), 16, 0, 0);   \
      __builtin_amdgcn_global_load_lds(                                        \
          (const __attribute__((address_space(1))) float*)                     \
              (reinterpret_cast<const char*>(elo_g) + go),                     \
          (__attribute__((address_space(3))) float*)(smem + lo_ + 16384),      \
          16, 0, 0);                                                           \
    }                                                                          \
  }

  STAGE_E(0, 0);

  const int col = lane & 15;
  const int g16 = (lane >> 4) * 16;
  bf16x8 a0h0, a0h1, a0l0, a0l1, a1h0, a1h1, a1l0, a1l1;
  {
    const char* zhb = smem + 32768;
    const char* zlb = smem + 49152;
    int pt0 = wv * 32 + col;
    int pt1 = pt0 + 16;
    int sw0 = (pt0 & 7) << 4, sw1 = (pt1 & 7) << 4;
    a0h0 = *reinterpret_cast<const bf16x8*>(zhb + pt0 * 128 + (g16 ^ sw0));
    a0h1 = *reinterpret_cast<const bf16x8*>(zhb + pt0 * 128 + ((64 + g16) ^ sw0));
    a0l0 = *reinterpret_cast<const bf16x8*>(zlb + pt0 * 128 + (g16 ^ sw0));
    a0l1 = *reinterpret_cast<const bf16x8*>(zlb + pt0 * 128 + ((64 + g16) ^ sw0));
    a1h0 = *reinterpret_cast<const bf16x8*>(zhb + pt1 * 128 + (g16 ^ sw1));
    a1h1 = *reinterpret_cast<const bf16x8*>(zhb + pt1 * 128 + ((64 + g16) ^ sw1));
    a1l0 = *reinterpret_cast<const bf16x8*>(zlb + pt1 * 128 + (g16 ^ sw1));
    a1l1 = *reinterpret_cast<const bf16x8*>(zlb + pt1 * 128 + ((64 + g16) ^ sw1));
  }
  __syncthreads();

  float s1a[2][4], s2a[2][4], s3a[2][4], i1a[2][4], i2a[2][4];
#pragma unroll
  for (int rt = 0; rt < 2; ++rt)
#pragma unroll
    for (int j = 0; j < 4; ++j) {
      s1a[rt][j] = 3.4e38f; s2a[rt][j] = 3.4e38f; s3a[rt][j] = 3.4e38f;
      i1a[rt][j] = 0.f; i2a[rt][j] = 0.f;
    }

  const int swc = (col & 7) << 4;

  for (int chunk = 0; chunk < 8; ++chunk) {
    const int cur = chunk & 1;
    if (chunk < 7) STAGE_E(cur ^ 1, chunk + 1);
    const char* ehb = smem + cur * 32768;
    const char* elb = ehb + 16384;

    for (int ct = 0; ct < 8; ++ct) {
      const int cl = ct * 16 + col;
      bf16x8 bh0 = *reinterpret_cast<const bf16x8*>(ehb + cl * 128 + (g16 ^ swc));
      bf16x8 bh1 = *reinterpret_cast<const bf16x8*>(ehb + cl * 128 + ((64 + g16) ^ swc));
      bf16x8 bl0 = *reinterpret_cast<const bf16x8*>(elb + cl * 128 + (g16 ^ swc));
      bf16x8 bl1 = *reinterpret_cast<const bf16x8*>(elb + cl * 128 + ((64 + g16) ^ swc));
      float half_esq = 0.5f * esq_s[chunk * 128 + cl];
      float fcode = (float)(chunk * 128 + cl);

      f32x4 acc0 = {0.f, 0.f, 0.f, 0.f};
      f32x4 acc1 = {0.f, 0.f, 0.f, 0.f};
      acc0 = __builtin_amdgcn_mfma_f32_16x16x32_bf16(a0h0, bh0, acc0, 0, 0, 0);
      acc1 = __builtin_amdgcn_mfma_f32_16x16x32_bf16(a1h0, bh0, acc1, 0, 0, 0);
      acc0 = __builtin_amdgcn_mfma_f32_16x16x32_bf16(a0h1, bh1, acc0, 0, 0, 0);
      acc1 = __builtin_amdgcn_mfma_f32_16x16x32_bf16(a1h1, bh1, acc1, 0, 0, 0);
      acc0 = __builtin_amdgcn_mfma_f32_16x16x32_bf16(a0h0, bl0, acc0, 0, 0, 0);
      acc1 = __builtin_amdgcn_mfma_f32_16x16x32_bf16(a1h0, bl0, acc1, 0, 0, 0);
      acc0 = __builtin_amdgcn_mfma_f32_16x16x32_bf16(a0h1, bl1, acc0, 0, 0, 0);
      acc1 = __builtin_amdgcn_mfma_f32_16x16x32_bf16(a1h1, bl1, acc1, 0, 0, 0);
      acc0 = __builtin_amdgcn_mfma_f32_16x16x32_bf16(a0l0, bh0, acc0, 0, 0, 0);
      acc1 = __builtin_amdgcn_mfma_f32_16x16x32_bf16(a1l0, bh0, acc1, 0, 0, 0);
      acc0 = __builtin_amdgcn_mfma_f32_16x16x32_bf16(a0l1, bh1, acc0, 0, 0, 0);
      acc1 = __builtin_amdgcn_mfma_f32_16x16x32_bf16(a1l1, bh1, acc1, 0, 0, 0);

#pragma unroll
      for (int j = 0; j < 4; ++j)
        ins3(half_esq - acc0[j], fcode, s1a[0][j], s2a[0][j], s3a[0][j],
             i1a[0][j], i2a[0][j]);
#pragma unroll
      for (int j = 0; j < 4; ++j)
        ins3(half_esq - acc1[j], fcode, s1a[1][j], s2a[1][j], s3a[1][j],
             i1a[1][j], i2a[1][j]);
    }
    __syncthreads();
  }
#undef STAGE_E

  const int g = lane >> 4;
  float* ps1 = part;
  float* pi1 = part + N_PTS;
  float* ps2 = part + 2 * N_PTS;
  float* pi2 = part + 3 * N_PTS;
  float* ps3 = part + 4 * N_PTS;
#pragma unroll
  for (int rt = 0; rt < 2; ++rt)
#pragma unroll
    for (int j = 0; j < 4; ++j) {
      float v1 = s1a[rt][j], w1i = i1a[rt][j];
      float v2 = s2a[rt][j], w2i = i2a[rt][j];
      float v3 = s3a[rt][j];
      merge3(v1, w1i, v2, w2i, v3, 1);
      merge3(v1, w1i, v2, w2i, v3, 2);
      merge3(v1, w1i, v2, w2i, v3, 4);
      merge3(v1, w1i, v2, w2i, v3, 8);
      if ((lane & 15) == j) {
        int n = bb + wv * 32 + rt * 16 + g * 4 + j;
        ps1[n] = v1; pi1[n] = w1i; ps2[n] = v2; pi2[n] = w2i; ps3[n] = v3;
      }
    }
}

// ---------------- K2: finalize, tie-resolve, gather/eq/loss, zt ----------------
__global__ __launch_bounds__(256) void k_combine(
    const float* __restrict__ Z, const float* __restrict__ E,
    const float* __restrict__ part,
    float* __restrict__ eq_out, float* __restrict__ idx_out,
    float* __restrict__ counts, float* __restrict__ loss_acc,
    float* __restrict__ zt) {
  __shared__ float lred[4];
  const int n = blockIdx.x * 256 + threadIdx.x;
  const int zbase = (n >> 12) * BSTRIDE + (n & 4095);

  float zr[64];
#pragma unroll
  for (int d = 0; d < 64; ++d) zr[d] = Z[zbase + d * HW];
  float zsq = 0.f;
#pragma unroll
  for (int d = 0; d < 64; ++d) zsq = fmaf(zr[d], zr[d], zsq);

  float w1 = zsq + 2.f * part[n];
  int i1g = (int)part[N_PTS + n];
  float w2 = zsq + 2.f * part[2 * N_PTS + n];
  int i2g = (int)part[3 * N_PTS + n];
  float w3 = zsq + 2.f * part[4 * N_PTS + n];

  if (zt) {
    float4* zt4 = reinterpret_cast<float4*>(zt + (size_t)n * 64);
#pragma unroll
    for (int j = 0; j < 16; ++j)
      zt4[j] = make_float4(zr[4 * j + 0], zr[4 * j + 1], zr[4 * j + 2], zr[4 * j + 3]);
  }

  int bi = i1g;
  if (w3 - w1 < MX_FULL) {
    double b = 1e300; int bb = 0;
    for (int c = 0; c < K_CODES; ++c) {
      const float* ep = E + c * D_DIM;
      double s = 0.0;
      for (int d = 0; d < 64; ++d) {
        double v = (double)zr[d] - (double)ep[d];
        s += v * v;
      }
      if (s < b) { b = s; bb = c; }
    }
    bi = bb;
  } else if (w2 - w1 < MX_RESCORE) {
    const float* ea = E + i1g * D_DIM;
    const float* eb = E + i2g * D_DIM;
    double da = 0.0, db = 0.0;
#pragma unroll
    for (int d = 0; d < 64; ++d) {
      double va = (double)zr[d] - (double)ea[d]; da += va * va;
      double vb = (double)zr[d] - (double)eb[d]; db += vb * vb;
    }
    if (db < da || (db == da && i2g < i1g)) bi = i2g;
  }

  idx_out[n] = (float)bi;
  atomicAdd(&counts[bi], 1.0f);

  const float4* er = reinterpret_cast<const float4*>(E + bi * D_DIM);
  float lsum = 0.f;
#pragma unroll
  for (int j = 0; j < 16; ++j) {
    float4 ev = er[j];
    int d = 4 * j;
    eq_out[zbase + (d + 0) * HW] = ev.x;
    eq_out[zbase + (d + 1) * HW] = ev.y;
    eq_out[zbase + (d + 2) * HW] = ev.z;
    eq_out[zbase + (d + 3) * HW] = ev.w;
    float f0 = ev.x - zr[d + 0], f1 = ev.y - zr[d + 1];
    float f2 = ev.z - zr[d + 2], f3 = ev.w - zr[d + 3];
    lsum = fmaf(f0, f0, lsum); lsum = fmaf(f1, f1, lsum);
    lsum = fmaf(f2, f2, lsum); lsum = fmaf(f3, f3, lsum);
  }
#pragma unroll
  for (int off = 32; off >= 1; off >>= 1) lsum += __shfl_xor(lsum, off, 64);
  int lane = threadIdx.x & 63, wid = threadIdx.x >> 6;
  if (lane == 0) lred[wid] = lsum;
  __syncthreads();
  if (threadIdx.x == 0)
    atomicAdd(loss_acc, lred[0] + lred[1] + lred[2] + lred[3]);
}

// ---------------- fallback: single-pass fp32 assign (if ws too small) ----------------
__global__ __launch_bounds__(256) void k_solo(
    const float* __restrict__ Z, const float* __restrict__ E,
    const float* __restrict__ esq,
    float* __restrict__ eq_out, float* __restrict__ idx_out,
    float* __restrict__ counts, float* __restrict__ loss_acc) {
  __shared__ float sE[CHUNK * D_DIM];
  __shared__ float sQ[CHUNK];
  int n = blockIdx.x * 256 + threadIdx.x;
  int zbase = (n >> 12) * BSTRIDE + (n & 4095);

  float zr[64];
#pragma unroll
  for (int d = 0; d < 64; ++d) zr[d] = Z[zbase + d * HW];
  float zsq = 0.f;
#pragma unroll
  for (int d = 0; d < 64; ++d) zsq = fmaf(zr[d], zr[d], zsq);

  float b1 = 3.4e38f, b2 = 3.4e38f, b3 = 3.4e38f;
  int i1 = 0, i2 = 0;
  for (int ch = 0; ch < K_CODES / CHUNK; ++ch) {
    __syncthreads();
    const float4* src = reinterpret_cast<const float4*>(E + ch * CHUNK * D_DIM);
    float4* dst = reinterpret_cast<float4*>(sE);
#pragma unroll
    for (int j = 0; j < 8; ++j) dst[threadIdx.x + 256 * j] = src[threadIdx.x + 256 * j];
    if (threadIdx.x < CHUNK) sQ[threadIdx.x] = esq[ch * CHUNK + threadIdx.x];
    __syncthreads();
    for (int c = 0; c < CHUNK; ++c) {
      const float4* ep = reinterpret_cast<const float4*>(sE + c * D_DIM);
      float d0 = 0.f, d1 = 0.f, d2 = 0.f, d3 = 0.f;
#pragma unroll
      for (int j = 0; j < 16; ++j) {
        float4 v = ep[j];
        d0 = fmaf(zr[4 * j + 0], v.x, d0);
        d1 = fmaf(zr[4 * j + 1], v.y, d1);
        d2 = fmaf(zr[4 * j + 2], v.z, d2);
        d3 = fmaf(zr[4 * j + 3], v.w, d3);
      }
      float dist = zsq + sQ[c] - 2.f * ((d0 + d1) + (d2 + d3));
      int cg = ch * CHUNK + c;
      bool lt1 = dist < b1, lt2 = dist < b2, lt3 = dist < b3;
      b3 = lt2 ? b2 : (lt3 ? dist : b3);
      b2 = lt1 ? b1 : (lt2 ? dist : b2);
      i2 = lt1 ? i1 : (lt2 ? cg : i2);
      b1 = lt1 ? dist : b1;
      i1 = lt1 ? cg : i1;
    }
  }
  int bi = i1;
  if (b3 - b1 < M_FULL) {
    double b = 1e300; int bb = 0;
    for (int c = 0; c < K_CODES; ++c) {
      const float* ep = E + c * D_DIM;
      double s = 0.0;
      for (int d = 0; d < 64; ++d) { double v = (double)zr[d] - (double)ep[d]; s += v * v; }
      if (s < b) { b = s; bb = c; }
    }
    bi = bb;
  } else if (b2 - b1 < M_RESCORE) {
    const float* ea = E + i1 * D_DIM;
    const float* eb = E + i2 * D_DIM;
    double da = 0.0, db = 0.0;
#pragma unroll
    for (int d = 0; d < 64; ++d) {
      double va = (double)zr[d] - (double)ea[d]; da += va * va;
      double vb = (double)zr[d] - (double)eb[d]; db += vb * vb;
    }
    if (db < da || (db == da && i2 < i1)) bi = i2;
  }

  idx_out[n] = (float)bi;
  atomicAdd(&counts[bi], 1.0f);
  const float4* er = reinterpret_cast<const float4*>(E + bi * D_DIM);
  float lsum = 0.f;
#pragma unroll
  for (int j = 0; j < 16; ++j) {
    float4 ev = er[j];
    int d = 4 * j;
    eq_out[zbase + (d + 0) * HW] = ev.x;
    eq_out[zbase + (d + 1) * HW] = ev.y;
    eq_out[zbase + (d + 2) * HW] = ev.z;
    eq_out[zbase + (d + 3) * HW] = ev.w;
    float f0 = ev.x - zr[d + 0], f1 = ev.y - zr[d + 1];
    float f2 = ev.z - zr[d + 2], f3 = ev.w - zr[d + 3];
    lsum = fmaf(f0, f0, lsum); lsum = fmaf(f1, f1, lsum);
    lsum = fmaf(f2, f2, lsum); lsum = fmaf(f3, f3, lsum);
  }
#pragma unroll
  for (int off = 32; off >= 1; off >>= 1) lsum += __shfl_xor(lsum, off, 64);
  if ((threadIdx.x & 63) == 0) atomicAdd(loss_acc, lsum);
}

// ---------------- K3: stats, smoothing scalars, threefry, prefix-sum ----------------
__global__ __launch_bounds__(1024) void k_stats(
    const float* __restrict__ counts, const float* __restrict__ cluster_size,
    float* __restrict__ out, float* __restrict__ ws,
    unsigned* __restrict__ rnd, const float* __restrict__ loss_acc,
    int* __restrict__ basep, int* __restrict__ cursorp) {
  __shared__ float red[16][4];
  __shared__ int sc[1024];
  int c = threadIdx.x;
  float cnt = counts[c];
  float csb = cluster_size[c] * 0.99f + cnt * 0.01f;
  out[OFF_CSB + c] = csb;

  float v_n = csb;
  float v_s = csb + 1e-5f;
  float p = cnt * (1.0f / 65536.0f);
  float v_p = p * logf(p + 1e-10f);
  float v_u = cnt > 0.f ? 1.f : 0.f;
#pragma unroll
  for (int off = 32; off >= 1; off >>= 1) {
    v_n += __shfl_xor(v_n, off, 64);
    v_s += __shfl_xor(v_s, off, 64);
    v_p += __shfl_xor(v_p, off, 64);
    v_u += __shfl_xor(v_u, off, 64);
  }
  int lane = threadIdx.x & 63, wid = threadIdx.x >> 6;
  if (lane == 0) { red[wid][0] = v_n; red[wid][1] = v_s; red[wid][2] = v_p; red[wid][3] = v_u; }
  __syncthreads();
  if (threadIdx.x == 0) {
    float nsum = 0.f, ssum = 0.f, psum = 0.f, usum = 0.f;
    for (int w = 0; w < 16; ++w) {
      nsum += red[w][0]; ssum += red[w][1]; psum += red[w][2]; usum += red[w][3];
    }
    ws[WS_NVAL] = nsum;
    ws[WS_SCS]  = ssum;
    out[OFF_STATS + 0] = expf(-psum);
    out[OFF_STATS + 1] = usum;
    out[OFF_LOSS] = 1.25f * loss_acc[0] * (1.0f / 4194304.0f);
  }
  rnd[c] = tf_rand_bits(c) & 0xFFFFu;

  if (basep) {
    int ci = (int)cnt;
    sc[c] = ci;
    __syncthreads();
    for (int off = 1; off < 1024; off <<= 1) {
      int v = (c >= off) ? sc[c - off] : 0;
      __syncthreads();
      sc[c] += v;
      __syncthreads();
    }
    int b = sc[c] - ci;
    basep[c] = b;
    cursorp[c] = b;
    if (c == 1023) basep[1024] = sc[1023];
  }
}

// ---------------- K3b: counting-sort scatter (packed code<<16|n) ----------------
__global__ __launch_bounds__(256) void k_scatter(
    const float* __restrict__ idxf, int* __restrict__ cursor,
    int* __restrict__ sorted) {
  int n = blockIdx.x * 256 + threadIdx.x;
  int bi = (int)idxf[n];
  int pos = atomicAdd(&cursor[bi], 1);
  sorted[pos] = (bi << 16) | n;
}

// ---------------- K4a: uniform-slice segmented embed_sum ----------------
__global__ __launch_bounds__(256) void k_esum(
    const float* __restrict__ zt, const int* __restrict__ sorted,
    float* __restrict__ esum) {
  const int d = threadIdx.x & 63, w = threadIdx.x >> 6;
  const int base = blockIdx.x * 128 + w * 32;
  // preload this wave's 32 packed entries (lanes 0-31 / dup in 32-63)
  int e_all = sorted[base + (threadIdx.x & 31)];
  float acc = 0.f;
  int curc = -1;
#pragma unroll
  for (int i = 0; i < 32; ++i) {
    int e = __shfl(e_all, i, 64);
    int c = e >> 16;
    int id = e & 0xFFFF;
    float v = zt[(size_t)id * 64 + d];
    if (c != curc) {
      if (curc >= 0) atomicAdd(&esum[curc * 64 + d], acc);
      acc = 0.f;
      curc = c;
    }
    acc += v;
  }
  if (curc >= 0) atomicAdd(&esum[curc * 64 + d], acc);
}

// ---------------- K4b: EMA + dead reinit + embedding ----------------
__global__ __launch_bounds__(256) void k_final(
    const float* __restrict__ zt, const float* __restrict__ embed_avg,
    const float* __restrict__ esum, const float* __restrict__ ws,
    const unsigned* __restrict__ rnd, float* __restrict__ out) {
  int idx = blockIdx.x * 256 + threadIdx.x;  // 0..65535
  int c = idx >> 6, d = idx & 63;
  float es = esum[idx];
  float csb = out[OFF_CSB + c];
  float nval = ws[WS_NVAL], scs = ws[WS_SCS];
  float cs = (csb + 1e-5f) / fmaxf(scs, 1e-8f) * nval;
  bool dead = cs < 1.0f;
  float csf = dead ? 1.0f : cs;
  float ea_ema = embed_avg[idx] * 0.99f + es * 0.01f;
  int r = (int)rnd[c];
  float zv = zt[(size_t)r * 64 + d];
  float ea = dead ? zv : ea_ema;
  out[OFF_EAB + idx] = ea;
  out[OFF_EMB + idx] = ea / csf;
}

// ---------------- K4 slow fallback: strided Z gather ----------------
__global__ __launch_bounds__(64) void k_update_slow(
    const float* __restrict__ Z, const float* __restrict__ embed_avg,
    const float* __restrict__ ws, const unsigned* __restrict__ rnd,
    const float* __restrict__ idxf, float* __restrict__ out) {
  const int c = blockIdx.x, d = threadIdx.x;
  const float cf = (float)c;
  float es = 0.f;
  const float4* i4 = reinterpret_cast<const float4*>(idxf);
  float4 cur = i4[d];
  for (int it = 0; it < 256; ++it) {
    float4 nxt = cur;
    if (it < 255) nxt = i4[(it + 1) * 64 + d];
    unsigned long long m0 = __ballot(cur.x == cf);
    unsigned long long m1 = __ballot(cur.y == cf);
    unsigned long long m2 = __ballot(cur.z == cf);
    unsigned long long m3 = __ballot(cur.w == cf);
    while (m0) { int b = __ffsll(m0) - 1; m0 &= m0 - 1;
      int p = it * 256 + b * 4 + 0; es += Z[(p >> 12) * BSTRIDE + d * HW + (p & 4095)]; }
    while (m1) { int b = __ffsll(m1) - 1; m1 &= m1 - 1;
      int p = it * 256 + b * 4 + 1; es += Z[(p >> 12) * BSTRIDE + d * HW + (p & 4095)]; }
    while (m2) { int b = __ffsll(m2) - 1; m2 &= m2 - 1;
      int p = it * 256 + b * 4 + 2; es += Z[(p >> 12) * BSTRIDE + d * HW + (p & 4095)]; }
    while (m3) { int b = __ffsll(m3) - 1; m3 &= m3 - 1;
      int p = it * 256 + b * 4 + 3; es += Z[(p >> 12) * BSTRIDE + d * HW + (p & 4095)]; }
    cur = nxt;
  }
  float csb = out[OFF_CSB + c];
  float nval = ws[WS_NVAL], scs = ws[WS_SCS];
  float cs = (csb + 1e-5f) / fmaxf(scs, 1e-8f) * nval;
  bool dead = cs < 1.0f;
  float csf = dead ? 1.0f : cs;
  float ea_ema = embed_avg[c * D_DIM + d] * 0.99f + es * 0.01f;
  int r = (int)rnd[c];
  float zv = Z[(r >> 12) * BSTRIDE + d * HW + (r & 4095)];
  float ea = dead ? zv : ea_ema;
  out[OFF_EAB + c * D_DIM + d] = ea;
  out[OFF_EMB + c * D_DIM + d] = ea / csf;
}

extern "C" void kernel_launch(void* const* d_in, const int* in_sizes, int n_in,
                              void* d_out, int out_size, void* d_ws, size_t ws_size,
                              hipStream_t stream) {
  const float* Z  = (const float*)d_in[0];
  const float* E  = (const float*)d_in[1];
  const float* CS = (const float*)d_in[2];
  const float* EA = (const float*)d_in[3];
  float* out = (float*)d_out;
  float* ws  = (float*)d_ws;
  unsigned* rnd = (unsigned*)(ws + WS_RAND);

  const size_t need = (size_t)(WS_ZT + (size_t)N_PTS * D_DIM + 16) * sizeof(float);
  const bool big = ws_size >= need;

  hipMemsetAsync(ws, 0, 1028 * sizeof(float), stream);
  if (big) {
    unsigned short* ehi = (unsigned short*)(ws + WS_EHI);
    unsigned short* elo = (unsigned short*)(ws + WS_ELO);
    float* esum  = ws + WS_ESUM;
    int* basep   = (int*)(ws + WS_BASE);
    int* cursorp = (int*)(ws + WS_CURS);
    int* sorted  = (int*)(ws + WS_SORT);
    float* zt = ws + WS_ZT;
    k_prep<<<256, 256, 0, stream>>>(E, ws + WS_ESQ, ehi, elo);
    k_assign_mfma<<<N_PTS / 128, 256, 0, stream>>>(Z, ehi, elo, ws + WS_ESQ, ws + WS_PART);
    k_combine<<<N_PTS / 256, 256, 0, stream>>>(Z, E, ws + WS_PART,
                                               out + OFF_EQ, out + OFF_IDX,
                                               ws + WS_CNT, ws + WS_LOSS, zt);
    // esum overlays ehi/elo -> zero it only after assign is done (stream-ordered)
    hipMemsetAsync(esum, 0, (size_t)K_CODES * D_DIM * sizeof(float), stream);
    k_stats<<<1, 1024, 0, stream>>>(ws + WS_CNT, CS, out, ws, rnd, ws + WS_LOSS,
                                    basep, cursorp);
    k_scatter<<<N_PTS / 256, 256, 0, stream>>>(out + OFF_IDX, cursorp, sorted);
    k_esum<<<N_PTS / 128, 256, 0, stream>>>(zt, sorted, esum);
    k_final<<<N_PTS / 256, 256, 0, stream>>>(zt, EA, esum, ws, rnd, out);
  } else {
    k_esq<<<4, 256, 0, stream>>>(E, ws + WS_ESQ);
    k_solo<<<N_PTS / 256, 256, 0, stream>>>(Z, E, ws + WS_ESQ,
                                            out + OFF_EQ, out + OFF_IDX,
                                            ws + WS_CNT, ws + WS_LOSS);
    k_stats<<<1, 1024, 0, stream>>>(ws + WS_CNT, CS, out, ws, rnd, ws + WS_LOSS,
                                    (int*)nullptr, (int*)nullptr);
    k_update_slow<<<K_CODES, 64, 0, stream>>>(Z, EA, ws, rnd, out + OFF_IDX, out);
  }
}

// Round 8
// 128.813 us; speedup vs baseline: 1.6146x; 1.0551x over previous
//
#include <hip/hip_runtime.h>
#include <math.h>

#define K_CODES 1024
#define D_DIM   64
#define N_PTS   65536
#define HW      4096
#define BSTRIDE 262144   // 64*4096 elements per batch image
#define CHUNK   128

// output offsets (floats)
#define OFF_EQ    0
#define OFF_IDX   4194304
#define OFF_LOSS  4259840
#define OFF_STATS 4259841
#define OFF_EMB   4259843
#define OFF_CSB   4325379
#define OFF_EAB   4326403

// workspace layout (float slots)
#define WS_LOSS 0
#define WS_NVAL 1
#define WS_SCS  2
#define WS_CNT  4
#define WS_ESQ  1028
#define WS_RAND 2052
#define WS_EHI  3076                   // 65536 ushort, swizzled bf16-hi (dead after assign)
#define WS_ELO  35844                  // 65536 ushort, swizzled bf16-lo (dead after assign)
#define WS_ESUM WS_EHI                 // float[65536] = 256KB, overlays EHI+ELO after assign
#define WS_PART 68612                  // 5 arrays of N: s1,i1,s2,i2,s3
#define WS_SORT WS_PART                // int[N] packed (code<<16|n), overlays part after combine
#define WS_BASE (WS_PART + N_PTS)      // int[1025], overlays part s2 (dead after combine)
#define WS_CURS (WS_PART + N_PTS + 1040) // int[1024]
#define WS_ZT   (WS_PART + 5 * N_PTS)  // transposed z: [N][64]

// fp32-exact fallback thresholds
#define M_RESCORE 0.01f
#define M_FULL    5e-4f
// MFMA-approx thresholds (dist error bound ~3e-3)
#define MX_RESCORE 0.05f
#define MX_FULL    8e-3f

typedef __attribute__((ext_vector_type(8))) __bf16 bf16x8;
typedef __attribute__((ext_vector_type(4))) float  f32x4;

// ---------------- bf16 split helpers ----------------
__device__ __forceinline__ unsigned short f2bf_rne(float x) {
  unsigned u = __float_as_uint(x);
  unsigned r = u + 0x7FFFu + ((u >> 16) & 1u);
  return (unsigned short)(r >> 16);
}
__device__ __forceinline__ float bf2f(unsigned short h) {
  return __uint_as_float(((unsigned)h) << 16);
}

// ---------------- threefry2x32 (JAX-compatible) ----------------
__device__ __forceinline__ void tf_block(unsigned k0, unsigned k1,
                                         unsigned& x0, unsigned& x1) {
  unsigned ks2 = k0 ^ k1 ^ 0x1BD11BDAu;
  x0 += k0; x1 += k1;
#define RR(r) { x0 += x1; x1 = (x1 << r) | (x1 >> (32 - r)); x1 ^= x0; }
  RR(13) RR(15) RR(26) RR(6)
  x0 += k1; x1 += ks2 + 1u;
  RR(17) RR(29) RR(16) RR(24)
  x0 += ks2; x1 += k0 + 2u;
  RR(13) RR(15) RR(26) RR(6)
  x0 += k0; x1 += k1 + 3u;
  RR(17) RR(29) RR(16) RR(24)
  x0 += k1; x1 += ks2 + 4u;
  RR(13) RR(15) RR(26) RR(6)
  x0 += ks2; x1 += k0 + 5u;
#undef RR
}

__device__ __forceinline__ unsigned tf_rand_bits(int c) {
  unsigned a0 = 0u, a1 = 2u; tf_block(0u, 1u, a0, a1);
  unsigned b0 = 1u, b1 = 3u; tf_block(0u, 1u, b0, b1);
  unsigned K0 = a1, K1 = b1;
  unsigned x0, x1;
  if (c < 512) { x0 = (unsigned)c; x1 = (unsigned)(512 + c); tf_block(K0, K1, x0, x1); return x0; }
  else         { x0 = (unsigned)(c - 512); x1 = (unsigned)c; tf_block(K0, K1, x0, x1); return x1; }
}

// ---------------- K0 (fallback path): codebook squared norms ----------------
__global__ void k_esq(const float* __restrict__ E, float* __restrict__ esq) {
  int c = blockIdx.x * blockDim.x + threadIdx.x;
  if (c >= K_CODES) return;
  const float4* e4 = reinterpret_cast<const float4*>(E + c * D_DIM);
  float s = 0.f;
#pragma unroll
  for (int j = 0; j < 16; ++j) {
    float4 v = e4[j];
    s += v.x * v.x + v.y * v.y + v.z * v.z + v.w * v.w;
  }
  esq[c] = s;
}

// ---------------- K0' (big path): fused esq + swizzled bf16 hi/lo split ----------------
__global__ __launch_bounds__(256) void k_prep(const float* __restrict__ E,
                                              float* __restrict__ esq,
                                              unsigned short* __restrict__ ehi,
                                              unsigned short* __restrict__ elo) {
  int idx = blockIdx.x * 256 + threadIdx.x;  // 0..65535; one wave == one code
  int c = idx >> 6, k = idx & 63;
  float v = E[idx];
  unsigned short h = f2bf_rne(v);
  unsigned short l = f2bf_rne(v - bf2f(h));
  int pos = (c << 6) | (k ^ ((c & 7) << 3));  // XOR-swizzle (16B granules)
  ehi[pos] = h;
  elo[pos] = l;
  float s = v * v;
#pragma unroll
  for (int off = 32; off >= 1; off >>= 1) s += __shfl_xor(s, off, 64);
  if (k == 0) esq[c] = s;
}

// ---------------- top-3 insert ----------------
__device__ __forceinline__ void ins3(float x, float ix, float& s1, float& s2,
                                     float& s3, float& i1, float& i2) {
  bool c1 = x < s1;
  bool c2 = x < s2;
  float n2 = __builtin_amdgcn_fmed3f(s1, s2, x);
  float n3 = __builtin_amdgcn_fmed3f(s2, s3, x);
  i2 = c1 ? i1 : (c2 ? ix : i2);
  i1 = c1 ? ix : i1;
  s1 = fminf(s1, x);
  s2 = n2;
  s3 = n3;
}

// ---------------- top-3 butterfly merge across 16-lane groups ----------------
__device__ __forceinline__ void merge3(float& a1, float& ai1, float& a2,
                                       float& ai2, float& a3, int off) {
  float b1  = __shfl_xor(a1, off, 64);
  float bi1 = __shfl_xor(ai1, off, 64);
  float b2  = __shfl_xor(a2, off, 64);
  float bi2 = __shfl_xor(ai2, off, 64);
  float b3  = __shfl_xor(a3, off, 64);
  bool f1 = a1 <= b1;
  float m1  = f1 ? a1 : b1;
  float mi1 = f1 ? ai1 : bi1;
  float hi  = f1 ? b1 : a1;
  float hii = f1 ? bi1 : ai1;
  bool f2 = a2 <= b2;
  float c2  = f2 ? a2 : b2;
  float ci2 = f2 ? ai2 : bi2;
  bool f3 = hi <= c2;
  float m2  = f3 ? hi : c2;
  float mi2 = f3 ? hii : ci2;
  float m3  = fminf(fmaxf(hi, c2), fminf(a3, b3));
  a1 = m1; ai1 = mi1; a2 = m2; ai2 = mi2; a3 = m3;
}

// ---------------- K1: MFMA distances, 128 pts/block, 8 waves x 16 pts ----------------
__global__ __launch_bounds__(512, 4) void k_assign_mfma(
    const float* __restrict__ Z, const unsigned short* __restrict__ ehi_g,
    const unsigned short* __restrict__ elo_g, const float* __restrict__ esq_g,
    float* __restrict__ part) {
  // [0,32K): E buf0 (hi 16K, lo 16K); [32K,64K): E buf1 / z-staging alias;
  // [64K,68K): esq (1024 f32)
  __shared__ __align__(16) char smem[69632];
  float* esq_s = reinterpret_cast<float*>(smem + 65536);

  const int tid  = threadIdx.x;
  const int lane = tid & 63;
  const int wv   = tid >> 6;          // 0..7
  const int bb   = blockIdx.x * 128;
  const int img  = bb >> 12;
  const int pix0 = bb & 4095;

#pragma unroll
  for (int r = 0; r < 2; ++r) esq_s[r * 512 + tid] = esq_g[r * 512 + tid];

  // ---- stage z into buf1 region: split bf16 hi/lo, swizzled ----
  {
    const int pt = tid & 127;
    const int grp = tid >> 7;                 // 0..3: dims 16*grp .. 16*grp+15
    const int gb = img * BSTRIDE + pix0 + pt;
    unsigned* zh32 = reinterpret_cast<unsigned*>(smem + 32768);
    unsigned* zl32 = reinterpret_cast<unsigned*>(smem + 49152);
    const int sw = (pt & 7) << 3;
#pragma unroll
    for (int it = 0; it < 8; ++it) {
      int k0 = grp * 16 + it * 2;
      float v0 = Z[gb + k0 * HW];
      float v1 = Z[gb + (k0 + 1) * HW];
      unsigned short h0 = f2bf_rne(v0);
      unsigned short h1 = f2bf_rne(v1);
      unsigned short l0 = f2bf_rne(v0 - bf2f(h0));
      unsigned short l1 = f2bf_rne(v1 - bf2f(h1));
      int ui = pt * 32 + ((k0 ^ sw) >> 1);
      zh32[ui] = (unsigned)h0 | ((unsigned)h1 << 16);
      zl32[ui] = (unsigned)l0 | ((unsigned)l1 << 16);
    }
  }
  __syncthreads();

#define STAGE_E(bsel, chk)                                                     \
  {                                                                            \
    _Pragma("unroll")                                                          \
    for (int r = 0; r < 2; ++r) {                                              \
      int go = (chk) * 16384 + (r * 512 + tid) * 16;                           \
      int lo_ = (bsel) * 32768 + (r * 512 + tid) * 16;                         \
      __builtin_amdgcn_global_load_lds(                                        \
          (const __attribute__((address_space(1))) float*)                     \
              (reinterpret_cast<const char*>(ehi_g) + go),                     \
          (__attribute__((address_space(3))) float*)(smem + lo_), 16, 0, 0);   \
      __builtin_amdgcn_global_load_lds(                                        \
          (const __attribute__((address_space(1))) float*)                     \
              (reinterpret_cast<const char*>(elo_g) + go),                     \
          (__attribute__((address_space(3))) float*)(smem + lo_ + 16384),      \
          16, 0, 0);                                                           \
    }                                                                          \
  }

  STAGE_E(0, 0);

  // ---- load A fragments (16 points per wave) from z region ----
  const int col = lane & 15;
  const int g16 = (lane >> 4) * 16;
  bf16x8 ah0, ah1, al0, al1;
  {
    const char* zhb = smem + 32768;
    const char* zlb = smem + 49152;
    int pt0 = wv * 16 + col;
    int sw0 = (pt0 & 7) << 4;
    ah0 = *reinterpret_cast<const bf16x8*>(zhb + pt0 * 128 + (g16 ^ sw0));
    ah1 = *reinterpret_cast<const bf16x8*>(zhb + pt0 * 128 + ((64 + g16) ^ sw0));
    al0 = *reinterpret_cast<const bf16x8*>(zlb + pt0 * 128 + (g16 ^ sw0));
    al1 = *reinterpret_cast<const bf16x8*>(zlb + pt0 * 128 + ((64 + g16) ^ sw0));
  }
  __syncthreads();  // chunk0 staged; z region free

  // ---- per-lane running top-3 state ----
  float s1a[4], s2a[4], s3a[4], i1a[4], i2a[4];
#pragma unroll
  for (int j = 0; j < 4; ++j) {
    s1a[j] = 3.4e38f; s2a[j] = 3.4e38f; s3a[j] = 3.4e38f;
    i1a[j] = 0.f; i2a[j] = 0.f;
  }

  const int swc = (col & 7) << 4;

  for (int chunk = 0; chunk < 8; ++chunk) {
    const int cur = chunk & 1;
    if (chunk < 7) STAGE_E(cur ^ 1, chunk + 1);
    const char* ehb = smem + cur * 32768;
    const char* elb = ehb + 16384;

    for (int ct = 0; ct < 8; ++ct) {
      const int cl = ct * 16 + col;
      bf16x8 bh0 = *reinterpret_cast<const bf16x8*>(ehb + cl * 128 + (g16 ^ swc));
      bf16x8 bh1 = *reinterpret_cast<const bf16x8*>(ehb + cl * 128 + ((64 + g16) ^ swc));
      bf16x8 bl0 = *reinterpret_cast<const bf16x8*>(elb + cl * 128 + (g16 ^ swc));
      bf16x8 bl1 = *reinterpret_cast<const bf16x8*>(elb + cl * 128 + ((64 + g16) ^ swc));
      float half_esq = 0.5f * esq_s[chunk * 128 + cl];
      float fcode = (float)(chunk * 128 + cl);

      f32x4 acc = {0.f, 0.f, 0.f, 0.f};
      acc = __builtin_amdgcn_mfma_f32_16x16x32_bf16(ah0, bh0, acc, 0, 0, 0);
      acc = __builtin_amdgcn_mfma_f32_16x16x32_bf16(ah1, bh1, acc, 0, 0, 0);
      acc = __builtin_amdgcn_mfma_f32_16x16x32_bf16(ah0, bl0, acc, 0, 0, 0);
      acc = __builtin_amdgcn_mfma_f32_16x16x32_bf16(ah1, bl1, acc, 0, 0, 0);
      acc = __builtin_amdgcn_mfma_f32_16x16x32_bf16(al0, bh0, acc, 0, 0, 0);
      acc = __builtin_amdgcn_mfma_f32_16x16x32_bf16(al1, bh1, acc, 0, 0, 0);

#pragma unroll
      for (int j = 0; j < 4; ++j)
        ins3(half_esq - acc[j], fcode, s1a[j], s2a[j], s3a[j], i1a[j], i2a[j]);
    }
    __syncthreads();
  }
#undef STAGE_E

  // ---- merge across the 16 lanes holding each point; write top-3 ----
  const int g = lane >> 4;
  float* ps1 = part;
  float* pi1 = part + N_PTS;
  float* ps2 = part + 2 * N_PTS;
  float* pi2 = part + 3 * N_PTS;
  float* ps3 = part + 4 * N_PTS;
#pragma unroll
  for (int j = 0; j < 4; ++j) {
    float v1 = s1a[j], w1i = i1a[j];
    float v2 = s2a[j], w2i = i2a[j];
    float v3 = s3a[j];
    merge3(v1, w1i, v2, w2i, v3, 1);
    merge3(v1, w1i, v2, w2i, v3, 2);
    merge3(v1, w1i, v2, w2i, v3, 4);
    merge3(v1, w1i, v2, w2i, v3, 8);
    if ((lane & 15) == j) {
      int n = bb + wv * 16 + g * 4 + j;
      ps1[n] = v1; pi1[n] = w1i; ps2[n] = v2; pi2[n] = w2i; ps3[n] = v3;
    }
  }
}

// ---------------- K2: finalize, tie-resolve, gather/eq/loss, zt ----------------
__global__ __launch_bounds__(256) void k_combine(
    const float* __restrict__ Z, const float* __restrict__ E,
    const float* __restrict__ part,
    float* __restrict__ eq_out, float* __restrict__ idx_out,
    float* __restrict__ counts, float* __restrict__ loss_acc,
    float* __restrict__ zt) {
  __shared__ float lred[4];
  const int n = blockIdx.x * 256 + threadIdx.x;
  const int zbase = (n >> 12) * BSTRIDE + (n & 4095);

  float zr[64];
#pragma unroll
  for (int d = 0; d < 64; ++d) zr[d] = Z[zbase + d * HW];
  float zsq = 0.f;
#pragma unroll
  for (int d = 0; d < 64; ++d) zsq = fmaf(zr[d], zr[d], zsq);

  float w1 = zsq + 2.f * part[n];
  int i1g = (int)part[N_PTS + n];
  float w2 = zsq + 2.f * part[2 * N_PTS + n];
  int i2g = (int)part[3 * N_PTS + n];
  float w3 = zsq + 2.f * part[4 * N_PTS + n];

  if (zt) {
    float4* zt4 = reinterpret_cast<float4*>(zt + (size_t)n * 64);
#pragma unroll
    for (int j = 0; j < 16; ++j)
      zt4[j] = make_float4(zr[4 * j + 0], zr[4 * j + 1], zr[4 * j + 2], zr[4 * j + 3]);
  }

  int bi = i1g;
  if (w3 - w1 < MX_FULL) {
    double b = 1e300; int bb = 0;
    for (int c = 0; c < K_CODES; ++c) {
      const float* ep = E + c * D_DIM;
      double s = 0.0;
      for (int d = 0; d < 64; ++d) {
        double v = (double)zr[d] - (double)ep[d];
        s += v * v;
      }
      if (s < b) { b = s; bb = c; }
    }
    bi = bb;
  } else if (w2 - w1 < MX_RESCORE) {
    const float* ea = E + i1g * D_DIM;
    const float* eb = E + i2g * D_DIM;
    double da = 0.0, db = 0.0;
#pragma unroll
    for (int d = 0; d < 64; ++d) {
      double va = (double)zr[d] - (double)ea[d]; da += va * va;
      double vb = (double)zr[d] - (double)eb[d]; db += vb * vb;
    }
    if (db < da || (db == da && i2g < i1g)) bi = i2g;
  }

  idx_out[n] = (float)bi;
  atomicAdd(&counts[bi], 1.0f);

  const float4* er = reinterpret_cast<const float4*>(E + bi * D_DIM);
  float lsum = 0.f;
#pragma unroll
  for (int j = 0; j < 16; ++j) {
    float4 ev = er[j];
    int d = 4 * j;
    eq_out[zbase + (d + 0) * HW] = ev.x;
    eq_out[zbase + (d + 1) * HW] = ev.y;
    eq_out[zbase + (d + 2) * HW] = ev.z;
    eq_out[zbase + (d + 3) * HW] = ev.w;
    float f0 = ev.x - zr[d + 0], f1 = ev.y - zr[d + 1];
    float f2 = ev.z - zr[d + 2], f3 = ev.w - zr[d + 3];
    lsum = fmaf(f0, f0, lsum); lsum = fmaf(f1, f1, lsum);
    lsum = fmaf(f2, f2, lsum); lsum = fmaf(f3, f3, lsum);
  }
#pragma unroll
  for (int off = 32; off >= 1; off >>= 1) lsum += __shfl_xor(lsum, off, 64);
  int lane = threadIdx.x & 63, wid = threadIdx.x >> 6;
  if (lane == 0) lred[wid] = lsum;
  __syncthreads();
  if (threadIdx.x == 0)
    atomicAdd(loss_acc, lred[0] + lred[1] + lred[2] + lred[3]);
}

// ---------------- fallback: single-pass fp32 assign (if ws too small) ----------------
__global__ __launch_bounds__(256) void k_solo(
    const float* __restrict__ Z, const float* __restrict__ E,
    const float* __restrict__ esq,
    float* __restrict__ eq_out, float* __restrict__ idx_out,
    float* __restrict__ counts, float* __restrict__ loss_acc) {
  __shared__ float sE[CHUNK * D_DIM];
  __shared__ float sQ[CHUNK];
  int n = blockIdx.x * 256 + threadIdx.x;
  int zbase = (n >> 12) * BSTRIDE + (n & 4095);

  float zr[64];
#pragma unroll
  for (int d = 0; d < 64; ++d) zr[d] = Z[zbase + d * HW];
  float zsq = 0.f;
#pragma unroll
  for (int d = 0; d < 64; ++d) zsq = fmaf(zr[d], zr[d], zsq);

  float b1 = 3.4e38f, b2 = 3.4e38f, b3 = 3.4e38f;
  int i1 = 0, i2 = 0;
  for (int ch = 0; ch < K_CODES / CHUNK; ++ch) {
    __syncthreads();
    const float4* src = reinterpret_cast<const float4*>(E + ch * CHUNK * D_DIM);
    float4* dst = reinterpret_cast<float4*>(sE);
#pragma unroll
    for (int j = 0; j < 8; ++j) dst[threadIdx.x + 256 * j] = src[threadIdx.x + 256 * j];
    if (threadIdx.x < CHUNK) sQ[threadIdx.x] = esq[ch * CHUNK + threadIdx.x];
    __syncthreads();
    for (int c = 0; c < CHUNK; ++c) {
      const float4* ep = reinterpret_cast<const float4*>(sE + c * D_DIM);
      float d0 = 0.f, d1 = 0.f, d2 = 0.f, d3 = 0.f;
#pragma unroll
      for (int j = 0; j < 16; ++j) {
        float4 v = ep[j];
        d0 = fmaf(zr[4 * j + 0], v.x, d0);
        d1 = fmaf(zr[4 * j + 1], v.y, d1);
        d2 = fmaf(zr[4 * j + 2], v.z, d2);
        d3 = fmaf(zr[4 * j + 3], v.w, d3);
      }
      float dist = zsq + sQ[c] - 2.f * ((d0 + d1) + (d2 + d3));
      int cg = ch * CHUNK + c;
      bool lt1 = dist < b1, lt2 = dist < b2, lt3 = dist < b3;
      b3 = lt2 ? b2 : (lt3 ? dist : b3);
      b2 = lt1 ? b1 : (lt2 ? dist : b2);
      i2 = lt1 ? i1 : (lt2 ? cg : i2);
      b1 = lt1 ? dist : b1;
      i1 = lt1 ? cg : i1;
    }
  }
  int bi = i1;
  if (b3 - b1 < M_FULL) {
    double b = 1e300; int bb = 0;
    for (int c = 0; c < K_CODES; ++c) {
      const float* ep = E + c * D_DIM;
      double s = 0.0;
      for (int d = 0; d < 64; ++d) { double v = (double)zr[d] - (double)ep[d]; s += v * v; }
      if (s < b) { b = s; bb = c; }
    }
    bi = bb;
  } else if (b2 - b1 < M_RESCORE) {
    const float* ea = E + i1 * D_DIM;
    const float* eb = E + i2 * D_DIM;
    double da = 0.0, db = 0.0;
#pragma unroll
    for (int d = 0; d < 64; ++d) {
      double va = (double)zr[d] - (double)ea[d]; da += va * va;
      double vb = (double)zr[d] - (double)eb[d]; db += vb * vb;
    }
    if (db < da || (db == da && i2 < i1)) bi = i2;
  }

  idx_out[n] = (float)bi;
  atomicAdd(&counts[bi], 1.0f);
  const float4* er = reinterpret_cast<const float4*>(E + bi * D_DIM);
  float lsum = 0.f;
#pragma unroll
  for (int j = 0; j < 16; ++j) {
    float4 ev = er[j];
    int d = 4 * j;
    eq_out[zbase + (d + 0) * HW] = ev.x;
    eq_out[zbase + (d + 1) * HW] = ev.y;
    eq_out[zbase + (d + 2) * HW] = ev.z;
    eq_out[zbase + (d + 3) * HW] = ev.w;
    float f0 = ev.x - zr[d + 0], f1 = ev.y - zr[d + 1];
    float f2 = ev.z - zr[d + 2], f3 = ev.w - zr[d + 3];
    lsum = fmaf(f0, f0, lsum); lsum = fmaf(f1, f1, lsum);
    lsum = fmaf(f2, f2, lsum); lsum = fmaf(f3, f3, lsum);
  }
#pragma unroll
  for (int off = 32; off >= 1; off >>= 1) lsum += __shfl_xor(lsum, off, 64);
  if ((threadIdx.x & 63) == 0) atomicAdd(loss_acc, lsum);
}

// ---------------- K3: stats, smoothing scalars, threefry, prefix-sum ----------------
__global__ __launch_bounds__(1024) void k_stats(
    const float* __restrict__ counts, const float* __restrict__ cluster_size,
    float* __restrict__ out, float* __restrict__ ws,
    unsigned* __restrict__ rnd, const float* __restrict__ loss_acc,
    int* __restrict__ basep, int* __restrict__ cursorp) {
  __shared__ float red[16][4];
  __shared__ int sc[1024];
  int c = threadIdx.x;
  float cnt = counts[c];
  float csb = cluster_size[c] * 0.99f + cnt * 0.01f;
  out[OFF_CSB + c] = csb;

  float v_n = csb;
  float v_s = csb + 1e-5f;
  float p = cnt * (1.0f / 65536.0f);
  float v_p = p * logf(p + 1e-10f);
  float v_u = cnt > 0.f ? 1.f : 0.f;
#pragma unroll
  for (int off = 32; off >= 1; off >>= 1) {
    v_n += __shfl_xor(v_n, off, 64);
    v_s += __shfl_xor(v_s, off, 64);
    v_p += __shfl_xor(v_p, off, 64);
    v_u += __shfl_xor(v_u, off, 64);
  }
  int lane = threadIdx.x & 63, wid = threadIdx.x >> 6;
  if (lane == 0) { red[wid][0] = v_n; red[wid][1] = v_s; red[wid][2] = v_p; red[wid][3] = v_u; }
  __syncthreads();
  if (threadIdx.x == 0) {
    float nsum = 0.f, ssum = 0.f, psum = 0.f, usum = 0.f;
    for (int w = 0; w < 16; ++w) {
      nsum += red[w][0]; ssum += red[w][1]; psum += red[w][2]; usum += red[w][3];
    }
    ws[WS_NVAL] = nsum;
    ws[WS_SCS]  = ssum;
    out[OFF_STATS + 0] = expf(-psum);
    out[OFF_STATS + 1] = usum;
    out[OFF_LOSS] = 1.25f * loss_acc[0] * (1.0f / 4194304.0f);
  }
  rnd[c] = tf_rand_bits(c) & 0xFFFFu;

  if (basep) {
    int ci = (int)cnt;
    sc[c] = ci;
    __syncthreads();
    for (int off = 1; off < 1024; off <<= 1) {
      int v = (c >= off) ? sc[c - off] : 0;
      __syncthreads();
      sc[c] += v;
      __syncthreads();
    }
    int b = sc[c] - ci;
    basep[c] = b;
    cursorp[c] = b;
    if (c == 1023) basep[1024] = sc[1023];
  }
}

// ---------------- K3b: counting-sort scatter (packed code<<16|n) ----------------
__global__ __launch_bounds__(256) void k_scatter(
    const float* __restrict__ idxf, int* __restrict__ cursor,
    int* __restrict__ sorted) {
  int n = blockIdx.x * 256 + threadIdx.x;
  int bi = (int)idxf[n];
  int pos = atomicAdd(&cursor[bi], 1);
  sorted[pos] = (bi << 16) | n;
}

// ---------------- K4a: uniform-slice segmented embed_sum ----------------
__global__ __launch_bounds__(256) void k_esum(
    const float* __restrict__ zt, const int* __restrict__ sorted,
    float* __restrict__ esum) {
  const int d = threadIdx.x & 63, w = threadIdx.x >> 6;
  const int base = blockIdx.x * 128 + w * 32;
  int e_all = sorted[base + (threadIdx.x & 31)];
  float acc = 0.f;
  int curc = -1;
#pragma unroll
  for (int i = 0; i < 32; ++i) {
    int e = __shfl(e_all, i, 64);
    int c = e >> 16;
    int id = e & 0xFFFF;
    float v = zt[(size_t)id * 64 + d];
    if (c != curc) {
      if (curc >= 0) atomicAdd(&esum[curc * 64 + d], acc);
      acc = 0.f;
      curc = c;
    }
    acc += v;
  }
  if (curc >= 0) atomicAdd(&esum[curc * 64 + d], acc);
}

// ---------------- K4b: EMA + dead reinit + embedding ----------------
__global__ __launch_bounds__(256) void k_final(
    const float* __restrict__ zt, const float* __restrict__ embed_avg,
    const float* __restrict__ esum, const float* __restrict__ ws,
    const unsigned* __restrict__ rnd, float* __restrict__ out) {
  int idx = blockIdx.x * 256 + threadIdx.x;  // 0..65535
  int c = idx >> 6, d = idx & 63;
  float es = esum[idx];
  float csb = out[OFF_CSB + c];
  float nval = ws[WS_NVAL], scs = ws[WS_SCS];
  float cs = (csb + 1e-5f) / fmaxf(scs, 1e-8f) * nval;
  bool dead = cs < 1.0f;
  float csf = dead ? 1.0f : cs;
  float ea_ema = embed_avg[idx] * 0.99f + es * 0.01f;
  int r = (int)rnd[c];
  float zv = zt[(size_t)r * 64 + d];
  float ea = dead ? zv : ea_ema;
  out[OFF_EAB + idx] = ea;
  out[OFF_EMB + idx] = ea / csf;
}

// ---------------- K4 slow fallback: strided Z gather ----------------
__global__ __launch_bounds__(64) void k_update_slow(
    const float* __restrict__ Z, const float* __restrict__ embed_avg,
    const float* __restrict__ ws, const unsigned* __restrict__ rnd,
    const float* __restrict__ idxf, float* __restrict__ out) {
  const int c = blockIdx.x, d = threadIdx.x;
  const float cf = (float)c;
  float es = 0.f;
  const float4* i4 = reinterpret_cast<const float4*>(idxf);
  float4 cur = i4[d];
  for (int it = 0; it < 256; ++it) {
    float4 nxt = cur;
    if (it < 255) nxt = i4[(it + 1) * 64 + d];
    unsigned long long m0 = __ballot(cur.x == cf);
    unsigned long long m1 = __ballot(cur.y == cf);
    unsigned long long m2 = __ballot(cur.z == cf);
    unsigned long long m3 = __ballot(cur.w == cf);
    while (m0) { int b = __ffsll(m0) - 1; m0 &= m0 - 1;
      int p = it * 256 + b * 4 + 0; es += Z[(p >> 12) * BSTRIDE + d * HW + (p & 4095)]; }
    while (m1) { int b = __ffsll(m1) - 1; m1 &= m1 - 1;
      int p = it * 256 + b * 4 + 1; es += Z[(p >> 12) * BSTRIDE + d * HW + (p & 4095)]; }
    while (m2) { int b = __ffsll(m2) - 1; m2 &= m2 - 1;
      int p = it * 256 + b * 4 + 2; es += Z[(p >> 12) * BSTRIDE + d * HW + (p & 4095)]; }
    while (m3) { int b = __ffsll(m3) - 1; m3 &= m3 - 1;
      int p = it * 256 + b * 4 + 3; es += Z[(p >> 12) * BSTRIDE + d * HW + (p & 4095)]; }
    cur = nxt;
  }
  float csb = out[OFF_CSB + c];
  float nval = ws[WS_NVAL], scs = ws[WS_SCS];
  float cs = (csb + 1e-5f) / fmaxf(scs, 1e-8f) * nval;
  bool dead = cs < 1.0f;
  float csf = dead ? 1.0f : cs;
  float ea_ema = embed_avg[c * D_DIM + d] * 0.99f + es * 0.01f;
  int r = (int)rnd[c];
  float zv = Z[(r >> 12) * BSTRIDE + d * HW + (r & 4095)];
  float ea = dead ? zv : ea_ema;
  out[OFF_EAB + c * D_DIM + d] = ea;
  out[OFF_EMB + c * D_DIM + d] = ea / csf;
}

extern "C" void kernel_launch(void* const* d_in, const int* in_sizes, int n_in,
                              void* d_out, int out_size, void* d_ws, size_t ws_size,
                              hipStream_t stream) {
  const float* Z  = (const float*)d_in[0];
  const float* E  = (const float*)d_in[1];
  const float* CS = (const float*)d_in[2];
  const float* EA = (const float*)d_in[3];
  float* out = (float*)d_out;
  float* ws  = (float*)d_ws;
  unsigned* rnd = (unsigned*)(ws + WS_RAND);

  const size_t need = (size_t)(WS_ZT + (size_t)N_PTS * D_DIM + 16) * sizeof(float);
  const bool big = ws_size >= need;

  hipMemsetAsync(ws, 0, 1028 * sizeof(float), stream);
  if (big) {
    unsigned short* ehi = (unsigned short*)(ws + WS_EHI);
    unsigned short* elo = (unsigned short*)(ws + WS_ELO);
    float* esum  = ws + WS_ESUM;
    int* basep   = (int*)(ws + WS_BASE);
    int* cursorp = (int*)(ws + WS_CURS);
    int* sorted  = (int*)(ws + WS_SORT);
    float* zt = ws + WS_ZT;
    k_prep<<<256, 256, 0, stream>>>(E, ws + WS_ESQ, ehi, elo);
    k_assign_mfma<<<N_PTS / 128, 512, 0, stream>>>(Z, ehi, elo, ws + WS_ESQ, ws + WS_PART);
    k_combine<<<N_PTS / 256, 256, 0, stream>>>(Z, E, ws + WS_PART,
                                               out + OFF_EQ, out + OFF_IDX,
                                               ws + WS_CNT, ws + WS_LOSS, zt);
    // esum overlays ehi/elo -> zero it only after assign is done (stream-ordered)
    hipMemsetAsync(esum, 0, (size_t)K_CODES * D_DIM * sizeof(float), stream);
    k_stats<<<1, 1024, 0, stream>>>(ws + WS_CNT, CS, out, ws, rnd, ws + WS_LOSS,
                                    basep, cursorp);
    k_scatter<<<N_PTS / 256, 256, 0, stream>>>(out + OFF_IDX, cursorp, sorted);
    k_esum<<<N_PTS / 128, 256, 0, stream>>>(zt, sorted, esum);
    k_final<<<N_PTS / 256, 256, 0, stream>>>(zt, EA, esum, ws, rnd, out);
  } else {
    k_esq<<<4, 256, 0, stream>>>(E, ws + WS_ESQ);
    k_solo<<<N_PTS / 256, 256, 0, stream>>>(Z, E, ws + WS_ESQ,
                                            out + OFF_EQ, out + OFF_IDX,
                                            ws + WS_CNT, ws + WS_LOSS);
    k_stats<<<1, 1024, 0, stream>>>(ws + WS_CNT, CS, out, ws, rnd, ws + WS_LOSS,
                                    (int*)nullptr, (int*)nullptr);
    k_update_slow<<<K_CODES, 64, 0, stream>>>(Z, EA, ws, rnd, out + OFF_IDX, out);
  }
}

// Round 9
// 119.218 us; speedup vs baseline: 1.7446x; 1.0805x over previous
//
#include <hip/hip_runtime.h>
#include <math.h>

#define K_CODES 1024
#define D_DIM   64
#define N_PTS   65536
#define HW      4096
#define BSTRIDE 262144   // 64*4096 elements per batch image
#define CHUNK   128

// output offsets (floats)
#define OFF_EQ    0
#define OFF_IDX   4194304
#define OFF_LOSS  4259840
#define OFF_STATS 4259841
#define OFF_EMB   4259843
#define OFF_CSB   4325379
#define OFF_EAB   4326403

// workspace layout (float slots)
#define WS_LOSS 0
#define WS_NVAL 1
#define WS_SCS  2
#define WS_CNT  4
#define WS_ESQ  1028
#define WS_RAND 2052
#define WS_EHI  3076                   // 65536 ushort, swizzled bf16-hi (dead after assign)
#define WS_ELO  35844                  // 65536 ushort, swizzled bf16-lo (dead after assign)
#define WS_ESUM WS_EHI                 // float[65536], overlays EHI+ELO after assign
#define WS_PART 68612                  // legacy region; SORT/BASE/CURS live here
#define WS_SORT WS_PART                // int[N] packed (code<<16|n)
#define WS_BASE (WS_PART + N_PTS)      // int[1025]
#define WS_CURS (WS_PART + N_PTS + 1040) // int[1024]
#define WS_ZT   (WS_PART + 5 * N_PTS)  // transposed z: [N][64]

// fp32-exact fallback thresholds
#define M_RESCORE 0.01f
#define M_FULL    5e-4f
// MFMA-approx thresholds (dist error bound ~3e-3)
#define MX_RESCORE 0.05f
#define MX_FULL    8e-3f

typedef __attribute__((ext_vector_type(8))) __bf16 bf16x8;
typedef __attribute__((ext_vector_type(4))) float  f32x4;

// ---------------- bf16 split helpers ----------------
__device__ __forceinline__ unsigned short f2bf_rne(float x) {
  unsigned u = __float_as_uint(x);
  unsigned r = u + 0x7FFFu + ((u >> 16) & 1u);
  return (unsigned short)(r >> 16);
}
__device__ __forceinline__ float bf2f(unsigned short h) {
  return __uint_as_float(((unsigned)h) << 16);
}

// ---------------- threefry2x32 (JAX-compatible) ----------------
__device__ __forceinline__ void tf_block(unsigned k0, unsigned k1,
                                         unsigned& x0, unsigned& x1) {
  unsigned ks2 = k0 ^ k1 ^ 0x1BD11BDAu;
  x0 += k0; x1 += k1;
#define RR(r) { x0 += x1; x1 = (x1 << r) | (x1 >> (32 - r)); x1 ^= x0; }
  RR(13) RR(15) RR(26) RR(6)
  x0 += k1; x1 += ks2 + 1u;
  RR(17) RR(29) RR(16) RR(24)
  x0 += ks2; x1 += k0 + 2u;
  RR(13) RR(15) RR(26) RR(6)
  x0 += k0; x1 += k1 + 3u;
  RR(17) RR(29) RR(16) RR(24)
  x0 += k1; x1 += ks2 + 4u;
  RR(13) RR(15) RR(26) RR(6)
  x0 += ks2; x1 += k0 + 5u;
#undef RR
}

__device__ __forceinline__ unsigned tf_rand_bits(int c) {
  unsigned a0 = 0u, a1 = 2u; tf_block(0u, 1u, a0, a1);
  unsigned b0 = 1u, b1 = 3u; tf_block(0u, 1u, b0, b1);
  unsigned K0 = a1, K1 = b1;
  unsigned x0, x1;
  if (c < 512) { x0 = (unsigned)c; x1 = (unsigned)(512 + c); tf_block(K0, K1, x0, x1); return x0; }
  else         { x0 = (unsigned)(c - 512); x1 = (unsigned)c; tf_block(K0, K1, x0, x1); return x1; }
}

// ---------------- K0 (fallback path): codebook squared norms ----------------
__global__ void k_esq(const float* __restrict__ E, float* __restrict__ esq) {
  int c = blockIdx.x * blockDim.x + threadIdx.x;
  if (c >= K_CODES) return;
  const float4* e4 = reinterpret_cast<const float4*>(E + c * D_DIM);
  float s = 0.f;
#pragma unroll
  for (int j = 0; j < 16; ++j) {
    float4 v = e4[j];
    s += v.x * v.x + v.y * v.y + v.z * v.z + v.w * v.w;
  }
  esq[c] = s;
}

// ---------------- K0': fused esq + swizzled bf16 hi/lo split + ws zero ----------------
__global__ __launch_bounds__(256) void k_prep(const float* __restrict__ E,
                                              float* __restrict__ esq,
                                              unsigned short* __restrict__ ehi,
                                              unsigned short* __restrict__ elo,
                                              float* __restrict__ ws0) {
  int idx = blockIdx.x * 256 + threadIdx.x;  // 0..65535; one wave == one code
  if (idx < 1028) ws0[idx] = 0.f;            // loss/nval/scs/counts
  int c = idx >> 6, k = idx & 63;
  float v = E[idx];
  unsigned short h = f2bf_rne(v);
  unsigned short l = f2bf_rne(v - bf2f(h));
  int pos = (c << 6) | (k ^ ((c & 7) << 3));  // XOR-swizzle (16B granules)
  ehi[pos] = h;
  elo[pos] = l;
  float s = v * v;
#pragma unroll
  for (int off = 32; off >= 1; off >>= 1) s += __shfl_xor(s, off, 64);
  if (k == 0) esq[c] = s;
}

// ---------------- top-3 insert ----------------
__device__ __forceinline__ void ins3(float x, float ix, float& s1, float& s2,
                                     float& s3, float& i1, float& i2) {
  bool c1 = x < s1;
  bool c2 = x < s2;
  float n2 = __builtin_amdgcn_fmed3f(s1, s2, x);
  float n3 = __builtin_amdgcn_fmed3f(s2, s3, x);
  i2 = c1 ? i1 : (c2 ? ix : i2);
  i1 = c1 ? ix : i1;
  s1 = fminf(s1, x);
  s2 = n2;
  s3 = n3;
}

// ---------------- top-3 butterfly merge across 16-lane groups ----------------
__device__ __forceinline__ void merge3(float& a1, float& ai1, float& a2,
                                       float& ai2, float& a3, int off) {
  float b1  = __shfl_xor(a1, off, 64);
  float bi1 = __shfl_xor(ai1, off, 64);
  float b2  = __shfl_xor(a2, off, 64);
  float bi2 = __shfl_xor(ai2, off, 64);
  float b3  = __shfl_xor(a3, off, 64);
  bool f1 = a1 <= b1;
  float m1  = f1 ? a1 : b1;
  float mi1 = f1 ? ai1 : bi1;
  float hi  = f1 ? b1 : a1;
  float hii = f1 ? bi1 : ai1;
  bool f2 = a2 <= b2;
  float c2  = f2 ? a2 : b2;
  float ci2 = f2 ? ai2 : bi2;
  bool f3 = hi <= c2;
  float m2  = f3 ? hi : c2;
  float mi2 = f3 ? hii : ci2;
  float m3  = fminf(fmaxf(hi, c2), fminf(a3, b3));
  a1 = m1; ai1 = mi1; a2 = m2; ai2 = mi2; a3 = m3;
}

// ---------------- K1: MFMA distances + fused combine epilogue ----------------
__global__ __launch_bounds__(512, 4) void k_assign_mfma(
    const float* __restrict__ Z, const float* __restrict__ E,
    const unsigned short* __restrict__ ehi_g,
    const unsigned short* __restrict__ elo_g, const float* __restrict__ esq_g,
    float* __restrict__ eq_out, float* __restrict__ idx_out,
    float* __restrict__ counts, float* __restrict__ loss_acc,
    float* __restrict__ zt) {
  // [0,32K): E buf0; [32K,64K): E buf1 / z-staging / epilogue z-f32;
  // [64K,68K): esq
  __shared__ __align__(16) char smem[69632];
  float* esq_s = reinterpret_cast<float*>(smem + 65536);

  const int tid  = threadIdx.x;
  const int lane = tid & 63;
  const int wv   = tid >> 6;          // 0..7
  const int bb   = blockIdx.x * 128;
  const int img  = bb >> 12;
  const int pix0 = bb & 4095;

#pragma unroll
  for (int r = 0; r < 2; ++r) esq_s[r * 512 + tid] = esq_g[r * 512 + tid];

  // ---- stage z into buf1 region: split bf16 hi/lo, swizzled ----
  {
    const int pt = tid & 127;
    const int grp = tid >> 7;                 // 0..3
    const int gb = img * BSTRIDE + pix0 + pt;
    unsigned* zh32 = reinterpret_cast<unsigned*>(smem + 32768);
    unsigned* zl32 = reinterpret_cast<unsigned*>(smem + 49152);
    const int sw = (pt & 7) << 3;
#pragma unroll
    for (int it = 0; it < 8; ++it) {
      int k0 = grp * 16 + it * 2;
      float v0 = Z[gb + k0 * HW];
      float v1 = Z[gb + (k0 + 1) * HW];
      unsigned short h0 = f2bf_rne(v0);
      unsigned short h1 = f2bf_rne(v1);
      unsigned short l0 = f2bf_rne(v0 - bf2f(h0));
      unsigned short l1 = f2bf_rne(v1 - bf2f(h1));
      int ui = pt * 32 + ((k0 ^ sw) >> 1);
      zh32[ui] = (unsigned)h0 | ((unsigned)h1 << 16);
      zl32[ui] = (unsigned)l0 | ((unsigned)l1 << 16);
    }
  }
  __syncthreads();

#define STAGE_E(bsel, chk)                                                     \
  {                                                                            \
    _Pragma("unroll")                                                          \
    for (int r = 0; r < 2; ++r) {                                              \
      int go = (chk) * 16384 + (r * 512 + tid) * 16;                           \
      int lo_ = (bsel) * 32768 + (r * 512 + tid) * 16;                         \
      __builtin_amdgcn_global_load_lds(                                        \
          (const __attribute__((address_space(1))) float*)                     \
              (reinterpret_cast<const char*>(ehi_g) + go),                     \
          (__attribute__((address_space(3))) float*)(smem + lo_), 16, 0, 0);   \
      __builtin_amdgcn_global_load_lds(                                        \
          (const __attribute__((address_space(1))) float*)                     \
              (reinterpret_cast<const char*>(elo_g) + go),                     \
          (__attribute__((address_space(3))) float*)(smem + lo_ + 16384),      \
          16, 0, 0);                                                           \
    }                                                                          \
  }

  STAGE_E(0, 0);

  // ---- load A fragments (16 points per wave) ----
  const int col = lane & 15;
  const int g16 = (lane >> 4) * 16;
  bf16x8 ah0, ah1, al0, al1;
  {
    const char* zhb = smem + 32768;
    const char* zlb = smem + 49152;
    int pt0 = wv * 16 + col;
    int sw0 = (pt0 & 7) << 4;
    ah0 = *reinterpret_cast<const bf16x8*>(zhb + pt0 * 128 + (g16 ^ sw0));
    ah1 = *reinterpret_cast<const bf16x8*>(zhb + pt0 * 128 + ((64 + g16) ^ sw0));
    al0 = *reinterpret_cast<const bf16x8*>(zlb + pt0 * 128 + (g16 ^ sw0));
    al1 = *reinterpret_cast<const bf16x8*>(zlb + pt0 * 128 + ((64 + g16) ^ sw0));
  }
  __syncthreads();

  float s1a[4], s2a[4], s3a[4], i1a[4], i2a[4];
#pragma unroll
  for (int j = 0; j < 4; ++j) {
    s1a[j] = 3.4e38f; s2a[j] = 3.4e38f; s3a[j] = 3.4e38f;
    i1a[j] = 0.f; i2a[j] = 0.f;
  }

  const int swc = (col & 7) << 4;

  for (int chunk = 0; chunk < 8; ++chunk) {
    const int cur = chunk & 1;
    if (chunk < 7) STAGE_E(cur ^ 1, chunk + 1);
    const char* ehb = smem + cur * 32768;
    const char* elb = ehb + 16384;

    for (int ct = 0; ct < 8; ++ct) {
      const int cl = ct * 16 + col;
      bf16x8 bh0 = *reinterpret_cast<const bf16x8*>(ehb + cl * 128 + (g16 ^ swc));
      bf16x8 bh1 = *reinterpret_cast<const bf16x8*>(ehb + cl * 128 + ((64 + g16) ^ swc));
      bf16x8 bl0 = *reinterpret_cast<const bf16x8*>(elb + cl * 128 + (g16 ^ swc));
      bf16x8 bl1 = *reinterpret_cast<const bf16x8*>(elb + cl * 128 + ((64 + g16) ^ swc));
      float half_esq = 0.5f * esq_s[chunk * 128 + cl];
      float fcode = (float)(chunk * 128 + cl);

      f32x4 acc = {0.f, 0.f, 0.f, 0.f};
      acc = __builtin_amdgcn_mfma_f32_16x16x32_bf16(ah0, bh0, acc, 0, 0, 0);
      acc = __builtin_amdgcn_mfma_f32_16x16x32_bf16(ah1, bh1, acc, 0, 0, 0);
      acc = __builtin_amdgcn_mfma_f32_16x16x32_bf16(ah0, bl0, acc, 0, 0, 0);
      acc = __builtin_amdgcn_mfma_f32_16x16x32_bf16(ah1, bl1, acc, 0, 0, 0);
      acc = __builtin_amdgcn_mfma_f32_16x16x32_bf16(al0, bh0, acc, 0, 0, 0);
      acc = __builtin_amdgcn_mfma_f32_16x16x32_bf16(al1, bh1, acc, 0, 0, 0);

#pragma unroll
      for (int j = 0; j < 4; ++j)
        ins3(half_esq - acc[j], fcode, s1a[j], s2a[j], s3a[j], i1a[j], i2a[j]);
    }
    __syncthreads();
  }
#undef STAGE_E

  // ======== fused combine epilogue ========
  // LDS reuse: smem+0: st arrays; smem+32768: exact fp32 z (swizzled)
  float* st_s1 = reinterpret_cast<float*>(smem);
  float* st_i1 = st_s1 + 128;
  float* st_s2 = st_s1 + 256;
  float* st_i2 = st_s1 + 384;
  float* st_s3 = st_s1 + 512;
  float* st_zs = st_s1 + 640;            // [4][128]
  int*   st_bi = reinterpret_cast<int*>(st_s1 + 1152);  // [128]
  float* st_lr = st_s1 + 1280;           // [8]
  float* zf    = reinterpret_cast<float*>(smem + 32768); // [128][64] swizzled

  // merge top-3 across 16-lane groups -> LDS
  const int g = lane >> 4;
#pragma unroll
  for (int j = 0; j < 4; ++j) {
    float v1 = s1a[j], w1i = i1a[j];
    float v2 = s2a[j], w2i = i2a[j];
    float v3 = s3a[j];
    merge3(v1, w1i, v2, w2i, v3, 1);
    merge3(v1, w1i, v2, w2i, v3, 2);
    merge3(v1, w1i, v2, w2i, v3, 4);
    merge3(v1, w1i, v2, w2i, v3, 8);
    if ((lane & 15) == j) {
      int p = wv * 16 + g * 4 + j;
      st_s1[p] = v1; st_i1[p] = w1i; st_s2[p] = v2; st_i2[p] = w2i; st_s3[p] = v3;
    }
  }

  // re-read exact fp32 z (L2-hot), zsq partials, zt write, z->LDS
  const int p   = tid & 127;
  const int grp = tid >> 7;
  const int n   = bb + p;
  const int zb  = img * BSTRIDE + pix0 + p;
  const int zsw = p & 31;
  float zr16[16];
  {
    float zs = 0.f;
#pragma unroll
    for (int k = 0; k < 16; ++k) {
      float v = Z[zb + (grp * 16 + k) * HW];
      zr16[k] = v;
      zs = fmaf(v, v, zs);
      zf[p * 64 + ((grp * 16 + k) ^ zsw)] = v;
    }
    st_zs[grp * 128 + p] = zs;
    float4* zt4 = reinterpret_cast<float4*>(zt + (size_t)n * 64 + grp * 16);
#pragma unroll
    for (int k = 0; k < 4; ++k)
      zt4[k] = make_float4(zr16[4 * k], zr16[4 * k + 1], zr16[4 * k + 2], zr16[4 * k + 3]);
  }
  __syncthreads();

  // owner thread per point: tie-resolve, idx, counts
  if (tid < 128) {
    const int pp = tid;
    const float* zfp = zf + pp * 64;
    const int sw = pp & 31;
    float zsq = ((st_zs[pp] + st_zs[128 + pp]) + st_zs[256 + pp]) + st_zs[384 + pp];
    float w1 = zsq + 2.f * st_s1[pp];
    float w2 = zsq + 2.f * st_s2[pp];
    float w3 = zsq + 2.f * st_s3[pp];
    int i1g = (int)st_i1[pp];
    int i2g = (int)st_i2[pp];
    int bi = i1g;
    if (w3 - w1 < MX_FULL) {
      double b = 1e300; int bb2 = 0;
      for (int c = 0; c < K_CODES; ++c) {
        const float* ep = E + c * D_DIM;
        double s = 0.0;
        for (int d = 0; d < 64; ++d) {
          double v = (double)zfp[d ^ sw] - (double)ep[d];
          s += v * v;
        }
        if (s < b) { b = s; bb2 = c; }
      }
      bi = bb2;
    } else if (w2 - w1 < MX_RESCORE) {
      const float* ea = E + i1g * D_DIM;
      const float* eb = E + i2g * D_DIM;
      double da = 0.0, db = 0.0;
      for (int d = 0; d < 64; ++d) {
        double zv = (double)zfp[d ^ sw];
        double va = zv - (double)ea[d]; da += va * va;
        double vb = zv - (double)eb[d]; db += vb * vb;
      }
      if (db < da || (db == da && i2g < i1g)) bi = i2g;
    }
    idx_out[bb + pp] = (float)bi;
    atomicAdd(&counts[bi], 1.0f);
    st_bi[pp] = bi;
  }
  __syncthreads();

  // eq write + loss (4 threads per point, 16 dims each)
  {
    int bi = st_bi[p];
    const float4* er = reinterpret_cast<const float4*>(E + bi * D_DIM + grp * 16);
    float lsum = 0.f;
#pragma unroll
    for (int k = 0; k < 4; ++k) {
      float4 ev = er[k];
      int d = grp * 16 + 4 * k;
      eq_out[zb + (d + 0) * HW] = ev.x;
      eq_out[zb + (d + 1) * HW] = ev.y;
      eq_out[zb + (d + 2) * HW] = ev.z;
      eq_out[zb + (d + 3) * HW] = ev.w;
      float f0 = ev.x - zr16[4 * k + 0], f1 = ev.y - zr16[4 * k + 1];
      float f2 = ev.z - zr16[4 * k + 2], f3 = ev.w - zr16[4 * k + 3];
      lsum = fmaf(f0, f0, lsum); lsum = fmaf(f1, f1, lsum);
      lsum = fmaf(f2, f2, lsum); lsum = fmaf(f3, f3, lsum);
    }
#pragma unroll
    for (int off = 32; off >= 1; off >>= 1) lsum += __shfl_xor(lsum, off, 64);
    if (lane == 0) st_lr[wv] = lsum;
    __syncthreads();
    if (tid == 0) {
      float t = 0.f;
#pragma unroll
      for (int w = 0; w < 8; ++w) t += st_lr[w];
      atomicAdd(loss_acc, t);
    }
  }
}

// ---------------- fallback: single-pass fp32 assign (if ws too small) ----------------
__global__ __launch_bounds__(256) void k_solo(
    const float* __restrict__ Z, const float* __restrict__ E,
    const float* __restrict__ esq,
    float* __restrict__ eq_out, float* __restrict__ idx_out,
    float* __restrict__ counts, float* __restrict__ loss_acc) {
  __shared__ float sE[CHUNK * D_DIM];
  __shared__ float sQ[CHUNK];
  int n = blockIdx.x * 256 + threadIdx.x;
  int zbase = (n >> 12) * BSTRIDE + (n & 4095);

  float zr[64];
#pragma unroll
  for (int d = 0; d < 64; ++d) zr[d] = Z[zbase + d * HW];
  float zsq = 0.f;
#pragma unroll
  for (int d = 0; d < 64; ++d) zsq = fmaf(zr[d], zr[d], zsq);

  float b1 = 3.4e38f, b2 = 3.4e38f, b3 = 3.4e38f;
  int i1 = 0, i2 = 0;
  for (int ch = 0; ch < K_CODES / CHUNK; ++ch) {
    __syncthreads();
    const float4* src = reinterpret_cast<const float4*>(E + ch * CHUNK * D_DIM);
    float4* dst = reinterpret_cast<float4*>(sE);
#pragma unroll
    for (int j = 0; j < 8; ++j) dst[threadIdx.x + 256 * j] = src[threadIdx.x + 256 * j];
    if (threadIdx.x < CHUNK) sQ[threadIdx.x] = esq[ch * CHUNK + threadIdx.x];
    __syncthreads();
    for (int c = 0; c < CHUNK; ++c) {
      const float4* ep = reinterpret_cast<const float4*>(sE + c * D_DIM);
      float d0 = 0.f, d1 = 0.f, d2 = 0.f, d3 = 0.f;
#pragma unroll
      for (int j = 0; j < 16; ++j) {
        float4 v = ep[j];
        d0 = fmaf(zr[4 * j + 0], v.x, d0);
        d1 = fmaf(zr[4 * j + 1], v.y, d1);
        d2 = fmaf(zr[4 * j + 2], v.z, d2);
        d3 = fmaf(zr[4 * j + 3], v.w, d3);
      }
      float dist = zsq + sQ[c] - 2.f * ((d0 + d1) + (d2 + d3));
      int cg = ch * CHUNK + c;
      bool lt1 = dist < b1, lt2 = dist < b2, lt3 = dist < b3;
      b3 = lt2 ? b2 : (lt3 ? dist : b3);
      b2 = lt1 ? b1 : (lt2 ? dist : b2);
      i2 = lt1 ? i1 : (lt2 ? cg : i2);
      b1 = lt1 ? dist : b1;
      i1 = lt1 ? cg : i1;
    }
  }
  int bi = i1;
  if (b3 - b1 < M_FULL) {
    double b = 1e300; int bb = 0;
    for (int c = 0; c < K_CODES; ++c) {
      const float* ep = E + c * D_DIM;
      double s = 0.0;
      for (int d = 0; d < 64; ++d) { double v = (double)zr[d] - (double)ep[d]; s += v * v; }
      if (s < b) { b = s; bb = c; }
    }
    bi = bb;
  } else if (b2 - b1 < M_RESCORE) {
    const float* ea = E + i1 * D_DIM;
    const float* eb = E + i2 * D_DIM;
    double da = 0.0, db = 0.0;
#pragma unroll
    for (int d = 0; d < 64; ++d) {
      double va = (double)zr[d] - (double)ea[d]; da += va * va;
      double vb = (double)zr[d] - (double)eb[d]; db += vb * vb;
    }
    if (db < da || (db == da && i2 < i1)) bi = i2;
  }

  idx_out[n] = (float)bi;
  atomicAdd(&counts[bi], 1.0f);
  const float4* er = reinterpret_cast<const float4*>(E + bi * D_DIM);
  float lsum = 0.f;
#pragma unroll
  for (int j = 0; j < 16; ++j) {
    float4 ev = er[j];
    int d = 4 * j;
    eq_out[zbase + (d + 0) * HW] = ev.x;
    eq_out[zbase + (d + 1) * HW] = ev.y;
    eq_out[zbase + (d + 2) * HW] = ev.z;
    eq_out[zbase + (d + 3) * HW] = ev.w;
    float f0 = ev.x - zr[d + 0], f1 = ev.y - zr[d + 1];
    float f2 = ev.z - zr[d + 2], f3 = ev.w - zr[d + 3];
    lsum = fmaf(f0, f0, lsum); lsum = fmaf(f1, f1, lsum);
    lsum = fmaf(f2, f2, lsum); lsum = fmaf(f3, f3, lsum);
  }
#pragma unroll
  for (int off = 32; off >= 1; off >>= 1) lsum += __shfl_xor(lsum, off, 64);
  if ((threadIdx.x & 63) == 0) atomicAdd(loss_acc, lsum);
}

// ---------------- K3: stats, smoothing scalars, threefry, fast prefix ----------------
__global__ __launch_bounds__(1024) void k_stats(
    const float* __restrict__ counts, const float* __restrict__ cluster_size,
    float* __restrict__ out, float* __restrict__ ws,
    unsigned* __restrict__ rnd, const float* __restrict__ loss_acc,
    int* __restrict__ basep, int* __restrict__ cursorp) {
  __shared__ float red[16][4];
  __shared__ int swave[16];
  __shared__ int swofs[16];
  int c = threadIdx.x;
  int lane = threadIdx.x & 63, wid = threadIdx.x >> 6;
  float cnt = counts[c];
  float csb = cluster_size[c] * 0.99f + cnt * 0.01f;
  out[OFF_CSB + c] = csb;

  float v_n = csb;
  float v_s = csb + 1e-5f;
  float pr = cnt * (1.0f / 65536.0f);
  float v_p = pr * logf(pr + 1e-10f);
  float v_u = cnt > 0.f ? 1.f : 0.f;
#pragma unroll
  for (int off = 32; off >= 1; off >>= 1) {
    v_n += __shfl_xor(v_n, off, 64);
    v_s += __shfl_xor(v_s, off, 64);
    v_p += __shfl_xor(v_p, off, 64);
    v_u += __shfl_xor(v_u, off, 64);
  }
  if (lane == 0) { red[wid][0] = v_n; red[wid][1] = v_s; red[wid][2] = v_p; red[wid][3] = v_u; }

  // wave-level inclusive prefix of counts
  int ci = (int)cnt;
  int pref = ci;
  if (basep) {
#pragma unroll
    for (int off = 1; off < 64; off <<= 1) {
      int v = __shfl_up(pref, off, 64);
      if (lane >= off) pref += v;
    }
    if (lane == 63) swave[wid] = pref;
  }
  __syncthreads();
  if (threadIdx.x == 0) {
    float nsum = 0.f, ssum = 0.f, psum = 0.f, usum = 0.f;
    for (int w = 0; w < 16; ++w) {
      nsum += red[w][0]; ssum += red[w][1]; psum += red[w][2]; usum += red[w][3];
    }
    ws[WS_NVAL] = nsum;
    ws[WS_SCS]  = ssum;
    out[OFF_STATS + 0] = expf(-psum);
    out[OFF_STATS + 1] = usum;
    out[OFF_LOSS] = 1.25f * loss_acc[0] * (1.0f / 4194304.0f);
  }
  rnd[c] = tf_rand_bits(c) & 0xFFFFu;

  if (basep) {
    if (threadIdx.x < 16) {
      int wtot = swave[threadIdx.x];
      int wp = wtot;
#pragma unroll
      for (int off = 1; off < 16; off <<= 1) {
        int v = __shfl_up(wp, off, 64);
        if ((int)threadIdx.x >= off) wp += v;
      }
      swofs[threadIdx.x] = wp - wtot;   // exclusive wave offset
      if (threadIdx.x == 15) basep[1024] = wp;
    }
    __syncthreads();
    int b = swofs[wid] + pref - ci;
    basep[c] = b;
    cursorp[c] = b;
  }
}

// ---------------- K3b: counting-sort scatter + esum zero ----------------
__global__ __launch_bounds__(256) void k_scatter(
    const float* __restrict__ idxf, int* __restrict__ cursor,
    int* __restrict__ sorted, float* __restrict__ esum) {
  int n = blockIdx.x * 256 + threadIdx.x;
  esum[n] = 0.f;                        // overlays dead ehi/elo; 65536 slots exactly
  int bi = (int)idxf[n];
  int pos = atomicAdd(&cursor[bi], 1);
  sorted[pos] = (bi << 16) | n;
}

// ---------------- K4a: uniform-slice segmented embed_sum ----------------
__global__ __launch_bounds__(256) void k_esum(
    const float* __restrict__ zt, const int* __restrict__ sorted,
    float* __restrict__ esum) {
  const int d = threadIdx.x & 63, w = threadIdx.x >> 6;
  const int base = blockIdx.x * 128 + w * 32;
  int e_all = sorted[base + (threadIdx.x & 31)];
  float acc = 0.f;
  int curc = -1;
#pragma unroll
  for (int i = 0; i < 32; ++i) {
    int e = __shfl(e_all, i, 64);
    int c = e >> 16;
    int id = e & 0xFFFF;
    float v = zt[(size_t)id * 64 + d];
    if (c != curc) {
      if (curc >= 0) atomicAdd(&esum[curc * 64 + d], acc);
      acc = 0.f;
      curc = c;
    }
    acc += v;
  }
  if (curc >= 0) atomicAdd(&esum[curc * 64 + d], acc);
}

// ---------------- K4b: EMA + dead reinit + embedding ----------------
__global__ __launch_bounds__(256) void k_final(
    const float* __restrict__ zt, const float* __restrict__ embed_avg,
    const float* __restrict__ esum, const float* __restrict__ ws,
    const unsigned* __restrict__ rnd, float* __restrict__ out) {
  int idx = blockIdx.x * 256 + threadIdx.x;  // 0..65535
  int c = idx >> 6, d = idx & 63;
  float es = esum[idx];
  float csb = out[OFF_CSB + c];
  float nval = ws[WS_NVAL], scs = ws[WS_SCS];
  float cs = (csb + 1e-5f) / fmaxf(scs, 1e-8f) * nval;
  bool dead = cs < 1.0f;
  float csf = dead ? 1.0f : cs;
  float ea_ema = embed_avg[idx] * 0.99f + es * 0.01f;
  int r = (int)rnd[c];
  float zv = zt[(size_t)r * 64 + d];
  float ea = dead ? zv : ea_ema;
  out[OFF_EAB + idx] = ea;
  out[OFF_EMB + idx] = ea / csf;
}

// ---------------- K4 slow fallback: strided Z gather ----------------
__global__ __launch_bounds__(64) void k_update_slow(
    const float* __restrict__ Z, const float* __restrict__ embed_avg,
    const float* __restrict__ ws, const unsigned* __restrict__ rnd,
    const float* __restrict__ idxf, float* __restrict__ out) {
  const int c = blockIdx.x, d = threadIdx.x;
  const float cf = (float)c;
  float es = 0.f;
  const float4* i4 = reinterpret_cast<const float4*>(idxf);
  float4 cur = i4[d];
  for (int it = 0; it < 256; ++it) {
    float4 nxt = cur;
    if (it < 255) nxt = i4[(it + 1) * 64 + d];
    unsigned long long m0 = __ballot(cur.x == cf);
    unsigned long long m1 = __ballot(cur.y == cf);
    unsigned long long m2 = __ballot(cur.z == cf);
    unsigned long long m3 = __ballot(cur.w == cf);
    while (m0) { int b = __ffsll(m0) - 1; m0 &= m0 - 1;
      int p = it * 256 + b * 4 + 0; es += Z[(p >> 12) * BSTRIDE + d * HW + (p & 4095)]; }
    while (m1) { int b = __ffsll(m1) - 1; m1 &= m1 - 1;
      int p = it * 256 + b * 4 + 1; es += Z[(p >> 12) * BSTRIDE + d * HW + (p & 4095)]; }
    while (m2) { int b = __ffsll(m2) - 1; m2 &= m2 - 1;
      int p = it * 256 + b * 4 + 2; es += Z[(p >> 12) * BSTRIDE + d * HW + (p & 4095)]; }
    while (m3) { int b = __ffsll(m3) - 1; m3 &= m3 - 1;
      int p = it * 256 + b * 4 + 3; es += Z[(p >> 12) * BSTRIDE + d * HW + (p & 4095)]; }
    cur = nxt;
  }
  float csb = out[OFF_CSB + c];
  float nval = ws[WS_NVAL], scs = ws[WS_SCS];
  float cs = (csb + 1e-5f) / fmaxf(scs, 1e-8f) * nval;
  bool dead = cs < 1.0f;
  float csf = dead ? 1.0f : cs;
  float ea_ema = embed_avg[c * D_DIM + d] * 0.99f + es * 0.01f;
  int r = (int)rnd[c];
  float zv = Z[(r >> 12) * BSTRIDE + d * HW + (r & 4095)];
  float ea = dead ? zv : ea_ema;
  out[OFF_EAB + c * D_DIM + d] = ea;
  out[OFF_EMB + c * D_DIM + d] = ea / csf;
}

extern "C" void kernel_launch(void* const* d_in, const int* in_sizes, int n_in,
                              void* d_out, int out_size, void* d_ws, size_t ws_size,
                              hipStream_t stream) {
  const float* Z  = (const float*)d_in[0];
  const float* E  = (const float*)d_in[1];
  const float* CS = (const float*)d_in[2];
  const float* EA = (const float*)d_in[3];
  float* out = (float*)d_out;
  float* ws  = (float*)d_ws;
  unsigned* rnd = (unsigned*)(ws + WS_RAND);

  const size_t need = (size_t)(WS_ZT + (size_t)N_PTS * D_DIM + 16) * sizeof(float);
  const bool big = ws_size >= need;

  if (big) {
    unsigned short* ehi = (unsigned short*)(ws + WS_EHI);
    unsigned short* elo = (unsigned short*)(ws + WS_ELO);
    float* esum  = ws + WS_ESUM;
    int* basep   = (int*)(ws + WS_BASE);
    int* cursorp = (int*)(ws + WS_CURS);
    int* sorted  = (int*)(ws + WS_SORT);
    float* zt = ws + WS_ZT;
    k_prep<<<256, 256, 0, stream>>>(E, ws + WS_ESQ, ehi, elo, ws);
    k_assign_mfma<<<N_PTS / 128, 512, 0, stream>>>(Z, E, ehi, elo, ws + WS_ESQ,
                                                   out + OFF_EQ, out + OFF_IDX,
                                                   ws + WS_CNT, ws + WS_LOSS, zt);
    k_stats<<<1, 1024, 0, stream>>>(ws + WS_CNT, CS, out, ws, rnd, ws + WS_LOSS,
                                    basep, cursorp);
    k_scatter<<<N_PTS / 256, 256, 0, stream>>>(out + OFF_IDX, cursorp, sorted, esum);
    k_esum<<<N_PTS / 128, 256, 0, stream>>>(zt, sorted, esum);
    k_final<<<N_PTS / 256, 256, 0, stream>>>(zt, EA, esum, ws, rnd, out);
  } else {
    hipMemsetAsync(ws, 0, 1028 * sizeof(float), stream);
    k_esq<<<4, 256, 0, stream>>>(E, ws + WS_ESQ);
    k_solo<<<N_PTS / 256, 256, 0, stream>>>(Z, E, ws + WS_ESQ,
                                            out + OFF_EQ, out + OFF_IDX,
                                            ws + WS_CNT, ws + WS_LOSS);
    k_stats<<<1, 1024, 0, stream>>>(ws + WS_CNT, CS, out, ws, rnd, ws + WS_LOSS,
                                    (int*)nullptr, (int*)nullptr);
    k_update_slow<<<K_CODES, 64, 0, stream>>>(Z, EA, ws, rnd, out + OFF_IDX, out);
  }
}